// Round 5
// baseline (2508.742 us; speedup 1.0000x reference)
//
#include <hip/hip_runtime.h>

#define R 64
#define NX 16384
#define NV 2048
#define NXP (NX+8)
#define NVP (NV+8)
#define TW 64
#define SPLIT_VM 8
#define SPLIT_X 64
#define SPLIT_QRX 32
#define SPLIT_QRV 8

#define DXf 1.220703125e-4f
#define DVf 0.0078125f
#define DTf 0.001f
#define PI_F 3.14159265358979323846f
#define FAC_E (-1.0f)
#define FAC_I (0.01f)
#define ZE_F (-1.0f)
#define ZI_F (1.0f)
#define SQRT_DXf 0.011048543456039806f
#define SQRT_DVf 0.08838834764831845f
#define ISQRT_DXf 90.50966799187808f
#define ISQRT_DVf 11.313708498984761f

// ---------------- workspace layout (float offsets), per-species stride SPS ----
#define X_OFF 0
#define V_OFF 1048576
#define S_OFF 1179648
#define S1_OFF 1183744
#define SQ_OFF 1187840
#define D_OFF 1191936
#define MATS_OFF 1196032      /* 8 mats: vplus,vminus,Vm,Vp,Vl,Vr,Vmq,Vpq */
#define SM_OFF 1228800        /* KL,KR,EpM,EmM finals */
#define R1IF_OFF 1269760      /* f32 Rinv */
#define KA_OFF 1277952        /* 64 x NXP padded */
#define KB_OFF 2327040        /* 64 x NXP padded ; L-phase aliases below */
#define LA_OFF KB_OFF
#define LB_OFF (KB_OFF+131584)
#define Q1L_OFF (KB_OFF+263168)
#define VQ_OFF (KB_OFF+394240)
#define PART_OFF 3376128      /* f32 partials: 4 mats x 64 splits x 4096 */
#define PARTQR_OFF 4424704    /* f64 partials: 32 x 4096 doubles */
#define GD_OFF 4686848        /* reduced f64 gram: 4096 doubles = 8192 floats */
#define SPS 4695040
// shared region
#define RHO_OFF 9390080
#define E_OFF 9406464
#define C_OFF 9422848
#define FFT1_OFF 9426944
#define FFT2_OFF 9459712
// d_out per-species layout
#define DOUT_SPS 1183744
#define DOUT_X 0
#define DOUT_S 1048576
#define DOUT_V 1052672

__device__ __forceinline__ float mm2(float a, float b) {
    return (a*b > 0.0f) ? ((fabsf(a) < fabsf(b)) ? a : b) : 0.0f;
}

// ---------------- generic weighted gram: C[a][b] = sum_x av(a,x)*bv(b,x) ------
// mode 0: 6 V-matrices   mode 1: Vm/Vp masks from Vq   mode 2: K_left/K_right
// mode 3: Ep_mat/Em_mat  mode 4: fused {KL,KR,EpM,EmM} (mats 0,1 = mode2; 2,3 = mode3)
__global__ __launch_bounds__(256) void k_gram(float* W, int mode, int a_off, int lda,
    int b_off, int ldb, int boff, int e_abs, float fac0, float fac1,
    int out_off, int N, int nsplit)
{
  int sp = blockIdx.z, mat = blockIdx.y, split = blockIdx.x;
  float* base = W + (size_t)sp*SPS;
  const float* A = base + a_off;
  const float* B = base + b_off;
  float fac = sp ? fac1 : fac0;
  float* outp = base + out_off + (size_t)(mat*nsplit + split)*4096;
  int chunk = N / nsplit;
  int xb0 = split * chunk;
  __shared__ float tA[TW][R+1], tB[TW][R+1];
  float acc[4][4] = {};
  int tid = threadIdx.x, ty = tid >> 4, tx = tid & 15;
  for (int xt = 0; xt < chunk; xt += TW) {
    for (int idx = tid; idx < TW*R; idx += 256) {
      int xi = idx & 63, r = idx >> 6;
      int x = xb0 + xt + xi;
      float av, bv;
      if (mode == 0) {
        float vv = A[(size_t)r*lda + x];
        float vs = ((float)x + 0.5f)*DVf - 8.0f;
        if (mat == 0)      { av = vv * (fmaxf(vs,0.f)*DVf); bv = vv; }
        else if (mat == 1) { av = vv * (fminf(vs,0.f)*DVf); bv = vv; }
        else if (mat == 2) { av = vv * ((vs<0.f)?DVf:0.f); bv = vv; }
        else if (mat == 3) { av = vv * ((vs>0.f)?DVf:0.f); bv = vv; }
        else if (mat == 4) { av = vv; bv = (x>=1)   ? (vv - A[(size_t)r*lda + x-1]) : 0.f; }
        else               { av = vv; bv = (x<NV-1) ? (A[(size_t)r*lda + x+1] - vv) : 0.f; }
      } else if (mode == 1) {
        float vv = A[(size_t)r*lda + x];
        float vs = ((float)x + 0.5f)*DVf - 8.0f;
        float w = (mat==0) ? ((vs<0.f)?DVf:0.f) : ((vs>0.f)?DVf:0.f);
        av = vv*w; bv = vv;
      } else if (mode == 2) {
        av = A[(size_t)r*lda + x];
        const float* Bp = B + (size_t)r*ldb + boff + x;
        bv = (mat==0) ? (Bp[0] - Bp[-1]) : (Bp[1] - Bp[0]);
      } else if (mode == 3) {
        float e = W[e_abs + x] * fac;
        float vv = A[(size_t)r*lda + x];
        av = vv * (((mat==0) ? fmaxf(e,0.f) : fminf(e,0.f)) * DXf);
        bv = vv;
      } else { // mode 4 fused
        if (mat < 2) {
          av = A[(size_t)r*lda + x];
          const float* Bp = B + (size_t)r*ldb + boff + x;
          bv = (mat==0) ? (Bp[0] - Bp[-1]) : (Bp[1] - Bp[0]);
        } else {
          float e = W[e_abs + x] * fac;
          float vv = A[(size_t)r*lda + x];
          av = vv * (((mat==2) ? fmaxf(e,0.f) : fminf(e,0.f)) * DXf);
          bv = vv;
        }
      }
      tA[xi][r] = av; tB[xi][r] = bv;
    }
    __syncthreads();
    for (int xi = 0; xi < TW; ++xi) {
      float a0 = tA[xi][ty*4+0], a1 = tA[xi][ty*4+1], a2 = tA[xi][ty*4+2], a3 = tA[xi][ty*4+3];
      float b0 = tB[xi][tx*4+0], b1 = tB[xi][tx*4+1], b2 = tB[xi][tx*4+2], b3 = tB[xi][tx*4+3];
      acc[0][0]+=a0*b0; acc[0][1]+=a0*b1; acc[0][2]+=a0*b2; acc[0][3]+=a0*b3;
      acc[1][0]+=a1*b0; acc[1][1]+=a1*b1; acc[1][2]+=a1*b2; acc[1][3]+=a1*b3;
      acc[2][0]+=a2*b0; acc[2][1]+=a2*b1; acc[2][2]+=a2*b2; acc[2][3]+=a2*b3;
      acc[3][0]+=a3*b0; acc[3][1]+=a3*b1; acc[3][2]+=a3*b2; acc[3][3]+=a3*b3;
    }
    __syncthreads();
  }
  #pragma unroll
  for (int i = 0; i < 4; ++i)
    #pragma unroll
    for (int j = 0; j < 4; ++j)
      outp[(ty*4+i)*64 + tx*4 + j] = acc[i][j];
}

// gram with fp64 accumulation for QR (A only)
__global__ __launch_bounds__(256) void k_gram_qr(float* W, int a_off, int lda, int aoff,
    int N, int nsplit, int outd_off)
{
  int sp = blockIdx.z, split = blockIdx.x;
  float* base = W + (size_t)sp*SPS;
  const float* A = base + a_off + aoff;
  double* outp = (double*)(base + outd_off) + (size_t)split*4096;
  int chunk = N / nsplit, x0 = split*chunk;
  __shared__ float tA[TW][R+1];
  double acc[4][4] = {};
  int tid = threadIdx.x, ty = tid >> 4, tx = tid & 15;
  for (int xt = 0; xt < chunk; xt += TW) {
    for (int idx = tid; idx < TW*R; idx += 256) {
      int xi = idx & 63, r = idx >> 6;
      tA[xi][r] = A[(size_t)r*lda + x0 + xt + xi];
    }
    __syncthreads();
    for (int xi = 0; xi < TW; ++xi) {
      double a0 = tA[xi][ty*4+0], a1 = tA[xi][ty*4+1], a2 = tA[xi][ty*4+2], a3 = tA[xi][ty*4+3];
      double b0 = tA[xi][tx*4+0], b1 = tA[xi][tx*4+1], b2 = tA[xi][tx*4+2], b3 = tA[xi][tx*4+3];
      acc[0][0]+=a0*b0; acc[0][1]+=a0*b1; acc[0][2]+=a0*b2; acc[0][3]+=a0*b3;
      acc[1][0]+=a1*b0; acc[1][1]+=a1*b1; acc[1][2]+=a1*b2; acc[1][3]+=a1*b3;
      acc[2][0]+=a2*b0; acc[2][1]+=a2*b1; acc[2][2]+=a2*b2; acc[2][3]+=a2*b3;
      acc[3][0]+=a3*b0; acc[3][1]+=a3*b1; acc[3][2]+=a3*b2; acc[3][3]+=a3*b3;
    }
    __syncthreads();
  }
  #pragma unroll
  for (int i = 0; i < 4; ++i)
    #pragma unroll
    for (int j = 0; j < 4; ++j)
      outp[(ty*4+i)*64 + tx*4 + j] = acc[i][j];
}

// parallel reduce of f32 partial mats: grid (nmats, 16, 2); 256-elem slice per block
__global__ __launch_bounds__(256) void k_reduce2(float* W, int src_off, int dst_off, int nsplit)
{
  int sp = blockIdx.z, mat = blockIdx.x;
  int e = blockIdx.y*256 + threadIdx.x;
  float* base = W + (size_t)sp*SPS;
  const float* src = base + src_off + (size_t)mat*nsplit*4096 + e;
  float s = 0;
  for (int k = 0; k < nsplit; ++k) s += src[(size_t)k*4096];
  base[dst_off + (size_t)mat*4096 + e] = s;
}

// parallel reduce of f64 QR gram partials: grid (16, 1, 2); 256-elem slice per block
__global__ __launch_bounds__(256) void k_reduced(float* W, int src_off, int dst_off, int nsplit)
{
  int sp = blockIdx.z;
  int e = blockIdx.x*256 + threadIdx.x;
  float* base = W + (size_t)sp*SPS;
  const double* src = (const double*)(base + src_off) + e;
  double s = 0;
  for (int k = 0; k < nsplit; ++k) s += src[(size_t)k*4096];
  ((double*)(base + dst_off))[e] = s;
}

// C[j][x] = alpha*d[j]* sum_r coef(r,j) * B[r][x];  coef = transA? A[j][r] : A[r][j]
// optional mirror store into dout (+ per-species DOUT_SPS) at dmir_off
__global__ __launch_bounds__(256) void k_rr(float* W, int a_off, int transA, int b_off,
    int ldb, int boff, int c_off, int ldc, int coff, int d_off, float alpha,
    float* dout, int dmir_off)
{
  int sp = blockIdx.z;
  float* base = W + (size_t)sp*SPS;
  const float* A = base + a_off;
  const float* B = base + b_off + boff;
  float* C = base + c_off + coff;
  float* M = (dmir_off >= 0) ? (dout + (size_t)sp*DOUT_SPS + dmir_off) : nullptr;
  __shared__ float tA[R][R+1];
  __shared__ float dsc[R];
  int tid = threadIdx.x;
  for (int idx = tid; idx < R*R; idx += 256) {
    int r = idx >> 6, j = idx & 63;
    tA[r][j] = transA ? A[j*R + r] : A[idx];
  }
  if (tid < R) dsc[tid] = (d_off >= 0) ? base[d_off + tid] : 1.0f;
  __syncthreads();
  int ty = tid >> 4, tx = tid & 15;
  int x0 = blockIdx.x*64 + tx*4;
  float acc[4][4] = {};
  for (int r = 0; r < R; ++r) {
    float4 bv = *(const float4*)(B + (size_t)r*ldb + x0);
    float a0 = tA[r][ty*4+0], a1 = tA[r][ty*4+1], a2 = tA[r][ty*4+2], a3 = tA[r][ty*4+3];
    acc[0][0]+=a0*bv.x; acc[0][1]+=a0*bv.y; acc[0][2]+=a0*bv.z; acc[0][3]+=a0*bv.w;
    acc[1][0]+=a1*bv.x; acc[1][1]+=a1*bv.y; acc[1][2]+=a1*bv.z; acc[1][3]+=a1*bv.w;
    acc[2][0]+=a2*bv.x; acc[2][1]+=a2*bv.y; acc[2][2]+=a2*bv.z; acc[2][3]+=a2*bv.w;
    acc[3][0]+=a3*bv.x; acc[3][1]+=a3*bv.y; acc[3][2]+=a3*bv.z; acc[3][3]+=a3*bv.w;
  }
  #pragma unroll
  for (int i = 0; i < 4; ++i) {
    int j = ty*4 + i;
    float s = alpha * dsc[j];
    float4 o = make_float4(acc[i][0]*s, acc[i][1]*s, acc[i][2]*s, acc[i][3]*s);
    *(float4*)(C + (size_t)j*ldc + x0) = o;
    if (M) *(float4*)(M + (size_t)j*ldc + x0) = o;
  }
}

// ghosts for 2-ghost K buffer
__global__ __launch_bounds__(256) void k_ghost2(float* W, int k_off)
{
  int sp = blockIdx.z;
  float* base = W + (size_t)sp*SPS;
  float* K = base + k_off;
  int tid = threadIdx.x;
  int j = tid & 63, c = tid >> 6;
  const float* M = base + MATS_OFF + ((c < 2) ? 2 : 3)*4096;
  int dst = (c==0)?2 : (c==1)?3 : (c==2)?(NX+4):(NX+5);
  int src = (c==0)?5 : (c==1)?4 : (c==2)?(NX+3):(NX+2);
  float s = 0;
  for (int m = 0; m < R; ++m) s += M[j*R + m] * K[(size_t)m*NXP + src];
  K[(size_t)j*NXP + dst] = s;
}

// ghosts for 1-ghost K buffer
__global__ __launch_bounds__(128) void k_ghost1(float* W, int k_off, int vm_idx, int vp_idx)
{
  int sp = blockIdx.z;
  float* base = W + (size_t)sp*SPS;
  float* K = base + k_off;
  int tid = threadIdx.x;
  int j = tid & 63, c = tid >> 6;
  const float* M = base + MATS_OFF + ((c==0)? vm_idx : vp_idx)*4096;
  int dst = (c==0)? 3 : (NX+4);
  int src = (c==0)? 4 : (NX+3);
  float s = 0;
  for (int m = 0; m < R; ++m) s += M[j*R + m] * K[(size_t)m*NXP + src];
  K[(size_t)j*NXP + dst] = s;
}

__global__ __launch_bounds__(256) void k_ghostL(float* W)
{
  int sp = blockIdx.z;
  float* base = W + (size_t)sp*SPS;
  for (int idx = threadIdx.x; idx < 512; idx += 256) {
    int which = idx >> 8; int r = (idx >> 2) & 63; int c = idx & 3;
    int col = (c < 2) ? (2 + c) : (NV + 4 + (c - 2));
    (base + (which ? LB_OFF : LA_OFF))[(size_t)r*NVP + col] = 0.f;
  }
}

// fused slope-limited flux divergence + extra term + SSPRK2 combine
__global__ __launch_bounds__(256) void k_flux(float* W, int U_off, int Kx_off, int ldkx,
    int kxoff, int useWin, int P_off, int Mi_off, int A2_off, int B2_off,
    int e_abs, float fac0, float fac1, float dh_inv, int N, int ldp,
    int stage, int orig_off, int out_off)
{
  int sp = blockIdx.z;
  float* base = W + (size_t)sp*SPS;
  const float* U  = base + U_off;
  const float* Kx = base + Kx_off;
  const float* Pm = base + P_off;
  const float* Mm = base + Mi_off;
  const float* Am = base + A2_off;
  const float* Bm = base + B2_off;
  float fac = sp ? fac1 : fac0;
  int x0 = blockIdx.x * 32;
  __shared__ float win[R][37];
  __shared__ float dLt[32][R+1];
  __shared__ float dRt[32][R+1];
  __shared__ float KTt[32][R+1];
  int tid = threadIdx.x;
  for (int idx = tid; idx < R*36; idx += 256) {
    int c = idx % 36, m = idx / 36;
    win[m][c] = U[(size_t)m*ldp + x0 + 2 + c];
  }
  __syncthreads();
  for (int idx = tid; idx < R*32; idx += 256) {
    int xi = idx & 31, m = idx >> 5;
    float u0 = win[m][xi], u1 = win[m][xi+1], u2 = win[m][xi+2], u3 = win[m][xi+3], u4 = win[m][xi+4];
    float d01 = u1-u0, d12 = u2-u1, d23 = u3-u2, d34 = u4-u3;
    float s1 = mm2(d01,d12), s2 = mm2(d12,d23), s3 = mm2(d23,d34);
    dLt[xi][m] = ((u2 + 0.5f*s2) - (u1 + 0.5f*s1)) * dh_inv;
    dRt[xi][m] = ((u3 - 0.5f*s3) - (u2 - 0.5f*s2)) * dh_inv;
    KTt[xi][m] = useWin ? u2 : Kx[(size_t)m*ldkx + kxoff + x0 + xi];
  }
  __syncthreads();
  int ty = tid >> 4, tx = tid & 15;
  int j0 = ty*4;
  float aP[4][2] = {}, aM[4][2] = {}, aA[4][2] = {}, aB[4][2] = {};
  for (int m = 0; m < R; ++m) {
    float dl0 = dLt[tx*2][m],   dl1 = dLt[tx*2+1][m];
    float dr0 = dRt[tx*2][m],   dr1 = dRt[tx*2+1][m];
    float kt0 = KTt[tx*2][m],   kt1 = KTt[tx*2+1][m];
    #pragma unroll
    for (int i = 0; i < 4; ++i) {
      float p = Pm[(j0+i)*R + m], q = Mm[(j0+i)*R + m];
      float a = Am[(j0+i)*R + m], b = Bm[(j0+i)*R + m];
      aP[i][0] += p*dl0; aP[i][1] += p*dl1;
      aM[i][0] += q*dr0; aM[i][1] += q*dr1;
      aA[i][0] += a*kt0; aA[i][1] += a*kt1;
      aB[i][0] += b*kt0; aB[i][1] += b*kt1;
    }
  }
  const float* orig = base + orig_off;
  float* out = base + out_off;
  for (int xx = 0; xx < 2; ++xx) {
    int x = x0 + tx*2 + xx;
    float w1, w2;
    if (e_abs >= 0) { float e = W[e_abs + x]; w1 = fac*fmaxf(e,0.f); w2 = fac*fminf(e,0.f); }
    else { float vs = ((float)x + 0.5f)*DVf - 8.0f; w1 = fmaxf(vs,0.f); w2 = fminf(vs,0.f); }
    #pragma unroll
    for (int i = 0; i < 4; ++i) {
      int j = j0 + i;
      float rhs = -(aP[i][xx] + aM[i][xx] + w1*aA[i][xx] + w2*aB[i][xx]);
      float uval = win[j][tx*2 + xx + 2];
      float res;
      if (stage == 1) res = uval + DTf*rhs;
      else res = 0.5f*(orig[(size_t)j*ldp + 4 + x] + uval + DTf*rhs);
      out[(size_t)j*ldp + 4 + x] = res;
    }
  }
}

// CholeskyQR1 tail, SINGLE WAVE (64 threads; barriers lower to waitcnt-only):
// chol(G)->R; lane-local blocked tri-inverse -> Rinv; T = A_top@Rinv (reg-cached col);
// LAPACK sign chain -> D; S_out = D*R*sscale (+ optional mirror to dout).
__global__ __launch_bounds__(64) void k_cholA(float* W, int gd_off,
    int a_off, int lda, int aoff, int sout_off, float sscale,
    float* dout, int dmir_off)
{
  int sp = blockIdx.z;
  float* base = W + (size_t)sp*SPS;
  const double* GD = (const double*)(base + gd_off);
  const float* A = base + a_off + aoff;
  float* Rinv = base + R1IF_OFF;
  __shared__ double G[R][R+1];
  __shared__ double Wi[R][R+1];
  __shared__ double T[R][R+1];
  __shared__ double Asd[R][R+1];
  __shared__ double Pb[32][33];
  __shared__ double dinv[R];
  __shared__ double dsh[R];
  int j = threadIdx.x;
  for (int i = 0; i < R; ++i) {
    G[i][j] = GD[i*R + j];
    Asd[i][j] = (double)A[(size_t)i*lda + j];
    Wi[i][j] = 0.0;
  }
  __syncthreads();
  // ---- Cholesky (upper), row-k broadcast ----
  for (int k = 0; k < R; ++k) {
    double ukk = sqrt(G[k][k]);     // broadcast read (pre-write, lockstep)
    double uin = 1.0 / ukk;
    __syncthreads();
    if (j > k) G[k][j] *= uin;
    else if (j == k) G[k][k] = ukk;
    __syncthreads();
    if (j > k) {
      double gkj = G[k][j];
      for (int i = k+1; i <= j; ++i) G[i][j] -= G[k][i]*gkj;   // G[k][i] broadcast
    }
    __syncthreads();
  }
  dinv[j] = 1.0 / G[j][j];
  Wi[j][j] = 0.0;  // placeholder; set below after dinv visible
  __syncthreads();
  Wi[j][j] = dinv[j];
  // ---- 32x32 diagonal-block tri-inverse: per-column, lane-local (no syncs) ----
  {
    int blo = j & 32;
    for (int t = 1; t < 32; ++t) {
      int i = j - t;
      if (i >= blo) {
        double s = 0;
        for (int m = i+1; m <= j; ++m) s += G[i][m]*Wi[m][j];
        Wi[i][j] = -s * dinv[i];
      }
    }
  }
  __syncthreads();
  // ---- off-diagonal: P = R12*W22 ; W12 = -W11*P ----
  for (int u = 0; u < 16; ++u) {
    int e = j + 64*u;
    int m = e >> 5, jj = 32 + (e & 31);
    double s = 0;
    for (int k2 = 32; k2 <= jj; ++k2) s += G[m][k2]*Wi[k2][jj];
    Pb[m][jj-32] = s;
  }
  __syncthreads();
  for (int u = 0; u < 16; ++u) {
    int e = j + 64*u;
    int i = e >> 5, jj = 32 + (e & 31);
    double s = 0;
    for (int m = i; m < 32; ++m) s += Wi[i][m]*Pb[m][jj-32];
    Wi[i][jj] = -s;
  }
  __syncthreads();
  // Rinv f32 out (lower triangle already zero)
  for (int i = 0; i < R; ++i) Rinv[i*R + j] = (float)Wi[i][j];
  // ---- register cache of Wi column j (static idx, rule #20) ----
  double w[R];
  #pragma unroll
  for (int m = 0; m < R; ++m) w[m] = Wi[m][j];
  // ---- T[x][j] = sum_m w[m]*Asd[m][x]  (Asd broadcast reads) ----
  for (int x = 0; x < R; ++x) {
    double s0=0, s1=0, s2=0, s3=0;
    #pragma unroll
    for (int m = 0; m < R; m += 4) {
      s0 += w[m+0]*Asd[m+0][x];
      s1 += w[m+1]*Asd[m+1][x];
      s2 += w[m+2]*Asd[m+2][x];
      s3 += w[m+3]*Asd[m+3][x];
    }
    T[x][j] = (s0+s1)+(s2+s3);
  }
  __syncthreads();
  // ---- LAPACK Householder sign chain ----
  for (int k = 0; k < R; ++k) {
    double tkk = T[k][k];           // broadcast read (pre-write)
    double d = (tkk >= 0.0) ? -1.0 : 1.0;
    if (j == k) dsh[k] = d;
    if (j > k) {
      double c = d * T[k][j] / (1.0 + fabs(tkk));
      for (int m = k+1; m < R; ++m) T[m][j] += c * T[m][k];   // T[m][k] broadcast
    }
    __syncthreads();
  }
  base[D_OFF + j] = (float)dsh[j];
  float* mir = (dmir_off >= 0) ? (dout + (size_t)sp*DOUT_SPS + dmir_off) : nullptr;
  for (int i = 0; i < R; ++i) {
    float v = (i <= j) ? (float)(dsh[i] * G[i][j] * (double)sscale) : 0.0f;
    base[sout_off + i*R + j] = v;
    if (mir) mir[i*R + j] = v;
  }
}

// S-step small combine from pre-reduced mats at SM_OFF
__global__ __launch_bounds__(256) void k_sstep(float* W, int stage)
{
  int sp = blockIdx.x;
  float* base = W + (size_t)sp*SPS;
  float fac = sp ? FAC_I : FAC_E;
  __shared__ float Ab[4096], Bb[4096], Cb[4096];
  int tid = threadIdx.x, ty = tid >> 4, tx = tid & 15;
  for (int e = tid; e < 4096; e += 256) {
    Ab[e] = base[SM_OFF + e];            // KL
    Bb[e] = base[SM_OFF + 4096 + e];     // KR
  }
  __syncthreads();
  const float* vpm = base + MATS_OFF + 0*4096;
  const float* vmm = base + MATS_OFF + 1*4096;
  const float* vlm = base + MATS_OFF + 4*4096;
  const float* vrm = base + MATS_OFF + 5*4096;
  float accV[4][4] = {}, accE[4][4] = {};
  for (int m = 0; m < R; ++m) {
    float kl[4], kr[4], vpj[4], vmj[4];
    #pragma unroll
    for (int i = 0; i < 4; ++i) { kl[i] = Ab[(ty*4+i)*64+m]; kr[i] = Bb[(ty*4+i)*64+m]; }
    #pragma unroll
    for (int j = 0; j < 4; ++j) { vpj[j] = vpm[(tx*4+j)*64+m]; vmj[j] = vmm[(tx*4+j)*64+m]; }
    #pragma unroll
    for (int i = 0; i < 4; ++i)
      #pragma unroll
      for (int j = 0; j < 4; ++j)
        accV[i][j] += kl[i]*vpj[j] + kr[i]*vmj[j];
  }
  __syncthreads();
  const float* Sin = base + ((stage==1)? S_OFF : S1_OFF);
  for (int e = tid; e < 4096; e += 256) {
    Cb[e] = Sin[e];
    Ab[e] = base[SM_OFF + 2*4096 + e];   // Ep_mat
  }
  __syncthreads();
  float t1[4][4] = {};
  for (int m = 0; m < R; ++m) {
    float ar[4], cj[4];
    #pragma unroll
    for (int i = 0; i < 4; ++i) ar[i] = Ab[(ty*4+i)*64+m];
    #pragma unroll
    for (int j = 0; j < 4; ++j) cj[j] = Cb[m*64 + tx*4+j];
    #pragma unroll
    for (int i = 0; i < 4; ++i)
      #pragma unroll
      for (int j = 0; j < 4; ++j) t1[i][j] += ar[i]*cj[j];
  }
  __syncthreads();
  #pragma unroll
  for (int i = 0; i < 4; ++i)
    #pragma unroll
    for (int j = 0; j < 4; ++j) Bb[(ty*4+i)*64 + tx*4+j] = t1[i][j];
  __syncthreads();
  for (int m = 0; m < R; ++m) {
    float ar[4], vj[4];
    #pragma unroll
    for (int i = 0; i < 4; ++i) ar[i] = Bb[(ty*4+i)*64+m];
    #pragma unroll
    for (int j = 0; j < 4; ++j) vj[j] = vlm[(tx*4+j)*64+m];
    #pragma unroll
    for (int i = 0; i < 4; ++i)
      #pragma unroll
      for (int j = 0; j < 4; ++j) accE[i][j] += ar[i]*vj[j];
  }
  __syncthreads();
  for (int e = tid; e < 4096; e += 256) Ab[e] = base[SM_OFF + 3*4096 + e];  // Em_mat
  __syncthreads();
  float t2[4][4] = {};
  for (int m = 0; m < R; ++m) {
    float ar[4], cj[4];
    #pragma unroll
    for (int i = 0; i < 4; ++i) ar[i] = Ab[(ty*4+i)*64+m];
    #pragma unroll
    for (int j = 0; j < 4; ++j) cj[j] = Cb[m*64 + tx*4+j];
    #pragma unroll
    for (int i = 0; i < 4; ++i)
      #pragma unroll
      for (int j = 0; j < 4; ++j) t2[i][j] += ar[i]*cj[j];
  }
  __syncthreads();
  #pragma unroll
  for (int i = 0; i < 4; ++i)
    #pragma unroll
    for (int j = 0; j < 4; ++j) Bb[(ty*4+i)*64 + tx*4+j] = t2[i][j];
  __syncthreads();
  for (int m = 0; m < R; ++m) {
    float ar[4], vj[4];
    #pragma unroll
    for (int i = 0; i < 4; ++i) ar[i] = Bb[(ty*4+i)*64+m];
    #pragma unroll
    for (int j = 0; j < 4; ++j) vj[j] = vrm[(tx*4+j)*64+m];
    #pragma unroll
    for (int i = 0; i < 4; ++i)
      #pragma unroll
      for (int j = 0; j < 4; ++j) accE[i][j] += ar[i]*vj[j];
  }
  #pragma unroll
  for (int i = 0; i < 4; ++i)
    #pragma unroll
    for (int j = 0; j < 4; ++j) {
      int e = (ty*4+i)*64 + tx*4+j;
      float rhs = accV[i][j] + fac*accE[i][j];
      if (stage == 1) base[S1_OFF + e] = base[S_OFF + e] + DTf*rhs;
      else base[S_OFF + e] = 0.5f*(base[S_OFF + e] + base[S1_OFF + e] + DTf*rhs);
    }
}

// charge moments: c = Z * S @ (V @ 1 * DV)
__global__ __launch_bounds__(256) void k_csolve(float* W)
{
  int sp = blockIdx.x;
  float* base = W + (size_t)sp*SPS;
  const float* V = base + V_OFF;
  const float* S = base + S_OFF;
  __shared__ float red[R][4];
  __shared__ float mass[R];
  int tid = threadIdx.x;
  int r = tid >> 2, q = tid & 3;
  float s = 0;
  for (int v = q; v < NV; v += 4) s += V[(size_t)r*NV + v];
  red[r][q] = s;
  __syncthreads();
  if (tid < R) mass[tid] = (red[tid][0]+red[tid][1]+red[tid][2]+red[tid][3]) * DVf;
  __syncthreads();
  if (tid < R) {
    float c = 0;
    for (int j = 0; j < R; ++j) c += S[tid*R + j] * mass[j];
    W[C_OFF + sp*R + tid] = c * (sp ? ZI_F : ZE_F);
  }
}

__global__ __launch_bounds__(256) void k_rho(float* W)
{
  int x = blockIdx.x*256 + threadIdx.x;
  float s = 0;
  for (int r = 0; r < R; ++r) s += W[X_OFF + (size_t)r*NX + x] * W[C_OFF + r];
  for (int r = 0; r < R; ++r) s += W[(size_t)SPS + X_OFF + (size_t)r*NX + x] * W[C_OFF + R + r];
  W[RHO_OFF + x] = s;
}

// -------- FFT: length-128 radix-2 DIT in LDS, 64 threads --------
__device__ inline void fft128fwd(float2* b, int t)
{
  __syncthreads();
  int r0 = (int)(__brev((unsigned)t) >> 25);
  int r1 = (int)(__brev((unsigned)(t+64)) >> 25);
  float2 a0 = b[r0], a1 = b[r1];
  __syncthreads();
  b[t] = a0; b[t+64] = a1;
  for (int s = 1; s <= 7; ++s) {
    __syncthreads();
    int half = 1 << (s-1);
    int jj = t & (half-1);
    int g  = t >> (s-1);
    int pos = (g << s) + jj;
    float ang = -2.0f*PI_F*(float)jj / (float)(1 << s);
    float sn, cs; sincosf(ang, &sn, &cs);
    float2 u = b[pos], wv = b[pos+half];
    float2 v = make_float2(wv.x*cs - wv.y*sn, wv.x*sn + wv.y*cs);
    b[pos] = make_float2(u.x+v.x, u.y+v.y);
    b[pos+half] = make_float2(u.x-v.x, u.y-v.y);
  }
}

// pass A: per-n1 length-128 FFT over n2 (stride 128) + four-step twiddle, write transposed
__global__ __launch_bounds__(64) void k_fftA(float* W, int rin_off, int cin_off, int out_off)
{
  __shared__ float2 bb[128];
  int n1 = blockIdx.x, t = threadIdx.x;
  if (rin_off >= 0) {
    const float* rin = W + rin_off;
    bb[t]    = make_float2(rin[n1 + 128*t], 0.f);
    bb[t+64] = make_float2(rin[n1 + 128*(t+64)], 0.f);
  } else {
    const float2* cin = (const float2*)(W + cin_off);
    bb[t] = cin[n1 + 128*t]; bb[t+64] = cin[n1 + 128*(t+64)];
  }
  fft128fwd(bb, t);
  __syncthreads();
  float2* outp = (float2*)(W + out_off);
  for (int kk = 0; kk < 2; ++kk) {
    int k2 = t + 64*kk;
    float ang = -2.0f*PI_F*(float)(n1*k2) * (1.0f/16384.0f);
    float sn, cs; sincosf(ang, &sn, &cs);
    float2 v = bb[k2];
    outp[k2*128 + n1] = make_float2(v.x*cs - v.y*sn, v.x*sn + v.y*cs);
  }
}

// pass B: per-k2 FFT over n1; spectral scale 1/(ik); write conj(H) in natural order
__global__ __launch_bounds__(64) void k_fftB(float* W, int in_off, int out_off)
{
  __shared__ float2 bb[128];
  int k2 = blockIdx.x, t = threadIdx.x;
  const float2* in = (const float2*)(W + in_off);
  bb[t] = in[k2*128 + t]; bb[t+64] = in[k2*128 + t + 64];
  fft128fwd(bb, t);
  __syncthreads();
  float2* outp = (float2*)(W + out_off);
  for (int kk = 0; kk < 2; ++kk) {
    int k1 = t + 64*kk;
    int j = k2 + 128*k1;
    float2 X = bb[k1];
    float2 Hc;
    if (j == 0) Hc = make_float2(0.f, 0.f);
    else {
      float kphys = PI_F * (float)((j < 8192) ? j : (j - 16384));
      Hc = make_float2(X.y / kphys, X.x / kphys);   // conj(rho_hat/(i k))
    }
    outp[j] = Hc;
  }
}

// pass D: final FFT pass, take Re()/N -> E
__global__ __launch_bounds__(64) void k_fftD(float* W, int in_off, int e_off)
{
  __shared__ float2 bb[128];
  int k2 = blockIdx.x, t = threadIdx.x;
  const float2* in = (const float2*)(W + in_off);
  bb[t] = in[k2*128 + t]; bb[t+64] = in[k2*128 + t + 64];
  fft128fwd(bb, t);
  __syncthreads();
  for (int kk = 0; kk < 2; ++kk) {
    int k1 = t + 64*kk;
    W[e_off + k2 + 128*k1] = bb[k1].x * (1.0f/16384.0f);
  }
}

// ----------------------------------------------------------------------------
extern "C" void kernel_launch(void* const* d_in, const int* in_sizes, int n_in,
                              void* d_out, int out_size, void* d_ws, size_t ws_size,
                              hipStream_t stream)
{
  float* W = (float*)d_ws;
  float* outp = (float*)d_out;
  const size_t FB = sizeof(float);
  // inputs: Xe, Se, Ve, Xi, Si, Vi
  hipMemcpyAsync(W + X_OFF, d_in[0], FB*(size_t)R*NX, hipMemcpyDeviceToDevice, stream);
  hipMemcpyAsync(W + S_OFF, d_in[1], FB*(size_t)R*R,  hipMemcpyDeviceToDevice, stream);
  hipMemcpyAsync(W + V_OFF, d_in[2], FB*(size_t)R*NV, hipMemcpyDeviceToDevice, stream);
  hipMemcpyAsync(W + (size_t)SPS + X_OFF, d_in[3], FB*(size_t)R*NX, hipMemcpyDeviceToDevice, stream);
  hipMemcpyAsync(W + (size_t)SPS + S_OFF, d_in[4], FB*(size_t)R*R,  hipMemcpyDeviceToDevice, stream);
  hipMemcpyAsync(W + (size_t)SPS + V_OFF, d_in[5], FB*(size_t)R*NV, hipMemcpyDeviceToDevice, stream);

  // V-derived matrices (vplus,vminus,Vm,Vp,Vl,Vr)
  k_gram<<<dim3(SPLIT_VM,6,2),256,0,stream>>>(W, 0, V_OFF, NV, V_OFF, NV, 0, -1, 0.f,0.f, PART_OFF, NV, SPLIT_VM);
  k_reduce2<<<dim3(6,16,2),256,0,stream>>>(W, PART_OFF, MATS_OFF, SPLIT_VM);

  auto poisson = [&]() {
    k_csolve<<<dim3(2),256,0,stream>>>(W);
    k_rho<<<dim3(NX/256),256,0,stream>>>(W);
    k_fftA<<<dim3(128),64,0,stream>>>(W, RHO_OFF, -1, FFT1_OFF);
    k_fftB<<<dim3(128),64,0,stream>>>(W, FFT1_OFF, FFT2_OFF);
    k_fftA<<<dim3(128),64,0,stream>>>(W, -1, FFT2_OFF, FFT1_OFF);
    k_fftD<<<dim3(128),64,0,stream>>>(W, FFT1_OFF, E_OFF);
  };

  // CholeskyQR1 + LAPACK-sign emulation; optional d_out mirrors
  auto qr = [&](int a_off, int lda, int aoff, int N_, int nsplit,
                int sout_off, float sscale, int xout_off, int xout_ld, float inv_s,
                int smir, int xmir) {
    k_gram_qr<<<dim3(nsplit,1,2),256,0,stream>>>(W, a_off, lda, aoff, N_, nsplit, PARTQR_OFF);
    k_reduced<<<dim3(16,1,2),256,0,stream>>>(W, PARTQR_OFF, GD_OFF, nsplit);
    k_cholA<<<dim3(1,1,2),64,0,stream>>>(W, GD_OFF, a_off, lda, aoff, sout_off, sscale, outp, smir);
    k_rr<<<dim3(N_/64,1,2),256,0,stream>>>(W, R1IF_OFF, 0, a_off, lda, aoff, xout_off, xout_ld, 0, D_OFF, inv_s, outp, xmir);
  };

  // ---------- Poisson #1 + K-step ----------
  poisson();
  k_rr<<<dim3(NX/64,1,2),256,0,stream>>>(W, S_OFF, 0, X_OFF, NX, 0, KA_OFF, NXP, 4, -1, 1.0f, nullptr, -1);
  k_ghost2<<<dim3(1,1,2),256,0,stream>>>(W, KA_OFF);
  k_flux<<<dim3(NX/32,1,2),256,0,stream>>>(W, KA_OFF, KA_OFF, NXP, 4, 1,
      MATS_OFF+0*4096, MATS_OFF+1*4096, MATS_OFF+4*4096, MATS_OFF+5*4096,
      E_OFF, FAC_E, FAC_I, 1.0f/DXf, NX, NXP, 1, 0, KB_OFF);
  k_ghost2<<<dim3(1,1,2),256,0,stream>>>(W, KB_OFF);
  k_flux<<<dim3(NX/32,1,2),256,0,stream>>>(W, KB_OFF, KB_OFF, NXP, 4, 1,
      MATS_OFF+0*4096, MATS_OFF+1*4096, MATS_OFF+4*4096, MATS_OFF+5*4096,
      E_OFF, FAC_E, FAC_I, 1.0f/DXf, NX, NXP, 2, KA_OFF, KA_OFF);
  qr(KA_OFF, NXP, 4, NX, SPLIT_QRX, S_OFF, SQRT_DXf, X_OFF, NX, ISQRT_DXf, -1, DOUT_X);

  // ---------- Poisson #2 + S-step ----------
  poisson();
  auto sstep_eval = [&](int stage) {
    int sin = (stage==1) ? S_OFF : S1_OFF;
    k_rr<<<dim3(NX/64,1,2),256,0,stream>>>(W, sin, 0, X_OFF, NX, 0, KA_OFF, NXP, 4, -1, 1.0f, nullptr, -1);
    k_ghost1<<<dim3(1,1,2),128,0,stream>>>(W, KA_OFF, 2, 3);
    k_gram<<<dim3(SPLIT_X,4,2),256,0,stream>>>(W, 4, X_OFF, NX, KA_OFF, NXP, 4, E_OFF, 1.0f, 1.0f, PART_OFF, NX, SPLIT_X);
    k_reduce2<<<dim3(4,16,2),256,0,stream>>>(W, PART_OFF, SM_OFF, SPLIT_X);
    k_sstep<<<dim3(2),256,0,stream>>>(W, stage);
  };
  sstep_eval(1);
  sstep_eval(2);

  // ---------- Poisson #3 + L-step ----------
  poisson();
  k_rr<<<dim3(NV/64,1,2),256,0,stream>>>(W, S_OFF, 1, V_OFF, NV, 0, LA_OFF, NVP, 4, -1, 1.0f, nullptr, -1);
  k_ghostL<<<dim3(1,1,2),256,0,stream>>>(W);
  auto leval = [&](int Lsrc, int stage, int Ldst, int Lorig) {
    qr(Lsrc, NVP, 4, NV, SPLIT_QRV, SQ_OFF, SQRT_DVf, VQ_OFF, NV, ISQRT_DVf, -1, -1);
    k_gram<<<dim3(SPLIT_VM,2,2),256,0,stream>>>(W, 1, VQ_OFF, NV, VQ_OFF, NV, 0, -1, 0.f,0.f, PART_OFF, NV, SPLIT_VM);
    k_reduce2<<<dim3(2,16,2),256,0,stream>>>(W, PART_OFF, MATS_OFF + 6*4096, SPLIT_VM);
    k_rr<<<dim3(NX/64,1,2),256,0,stream>>>(W, SQ_OFF, 0, X_OFF, NX, 0, KA_OFF, NXP, 4, -1, 1.0f, nullptr, -1);
    k_ghost1<<<dim3(1,1,2),128,0,stream>>>(W, KA_OFF, 6, 7);
    k_gram<<<dim3(SPLIT_X,4,2),256,0,stream>>>(W, 4, X_OFF, NX, KA_OFF, NXP, 4, E_OFF, FAC_E, FAC_I, PART_OFF, NX, SPLIT_X);
    k_reduce2<<<dim3(4,16,2),256,0,stream>>>(W, PART_OFF, SM_OFF, SPLIT_X);
    k_flux<<<dim3(NV/32,1,2),256,0,stream>>>(W, Lsrc, VQ_OFF, NV, 0, 0,
        SM_OFF+2*4096, SM_OFF+3*4096, SM_OFF+0*4096, SM_OFF+1*4096,
        -1, 0.f, 0.f, 1.0f/DVf, NV, NVP, stage, Lorig, Ldst);
  };
  leval(LA_OFF, 1, LB_OFF, 0);
  leval(LB_OFF, 2, LA_OFF, LA_OFF);
  qr(LA_OFF, NVP, 4, NV, SPLIT_QRV, S_OFF, SQRT_DVf, V_OFF, NV, ISQRT_DVf, DOUT_S, DOUT_V);

  (void)in_sizes; (void)n_in; (void)out_size; (void)ws_size;
}

// Round 6
// 1743.092 us; speedup vs baseline: 1.4392x; 1.4392x over previous
//
#include <hip/hip_runtime.h>

#define R 64
#define NX 16384
#define NV 2048
#define NXP (NX+8)
#define NVP (NV+8)
#define TW 64
#define SPLIT_VM 8
#define SPLIT_X 64
#define SPLIT_QRX 128
#define SPLIT_QRV 32

#define DXf 1.220703125e-4f
#define DVf 0.0078125f
#define DTf 0.001f
#define PI_F 3.14159265358979323846f
#define FAC_E (-1.0f)
#define FAC_I (0.01f)
#define ZE_F (-1.0f)
#define ZI_F (1.0f)
#define SQRT_DXf 0.011048543456039806f
#define SQRT_DVf 0.08838834764831845f
#define ISQRT_DXf 90.50966799187808f
#define ISQRT_DVf 11.313708498984761f

// ---------------- workspace layout (float offsets), per-species stride SPS ----
#define X_OFF 0
#define V_OFF 1048576
#define S_OFF 1179648
#define S1_OFF 1183744
#define SQ_OFF 1187840
#define D_OFF 1191936
#define MATS_OFF 1196032      /* 8 mats: vplus,vminus,Vm,Vp,Vl,Vr,Vmq,Vpq */
#define SM_OFF 1228800        /* KL,KR,EpM,EmM finals */
#define R1IF_OFF 1269760      /* f32 Rinv */
#define KA_OFF 1277952        /* 64 x NXP padded */
#define KB_OFF 2327040        /* 64 x NXP padded ; L-phase aliases below */
#define LA_OFF KB_OFF
#define LB_OFF (KB_OFF+131584)
#define VQ_OFF (KB_OFF+394240)
#define PART_OFF 3376128      /* f32 partials 4x64x4096 ; aliased as f64 QR partials (max 128x4096 dbl = 4MB) */
#define PARTQR_OFF PART_OFF
#define GD_OFF 4686848        /* reduced f64 gram: 4096 doubles = 8192 floats */
#define SPS 4695040
// shared region
#define RHO_OFF 9390080
#define E_OFF 9406464
#define C_OFF 9422848
#define FFT1_OFF 9426944
#define FFT2_OFF 9459712
// d_out per-species layout
#define DOUT_SPS 1183744
#define DOUT_X 0
#define DOUT_S 1048576
#define DOUT_V 1052672

__device__ __forceinline__ float mm2(float a, float b) {
    return (a*b > 0.0f) ? ((fabsf(a) < fabsf(b)) ? a : b) : 0.0f;
}

// ---------------- generic weighted gram: C[a][b] = sum_x av(a,x)*bv(b,x) ------
// mode 0: 6 V-matrices   mode 1: Vm/Vp masks from Vq   mode 2: K_left/K_right
// mode 3: Ep_mat/Em_mat  mode 4: fused {KL,KR,EpM,EmM}
__global__ __launch_bounds__(256) void k_gram(float* W, int mode, int a_off, int lda,
    int b_off, int ldb, int boff, int e_abs, float fac0, float fac1,
    int out_off, int N, int nsplit)
{
  int sp = blockIdx.z, mat = blockIdx.y, split = blockIdx.x;
  float* base = W + (size_t)sp*SPS;
  const float* A = base + a_off;
  const float* B = base + b_off;
  float fac = sp ? fac1 : fac0;
  float* outp = base + out_off + (size_t)(mat*nsplit + split)*4096;
  int chunk = N / nsplit;
  int xb0 = split * chunk;
  __shared__ float tA[TW][R+1], tB[TW][R+1];
  float acc[4][4] = {};
  int tid = threadIdx.x, ty = tid >> 4, tx = tid & 15;
  for (int xt = 0; xt < chunk; xt += TW) {
    for (int idx = tid; idx < TW*R; idx += 256) {
      int xi = idx & 63, r = idx >> 6;
      int x = xb0 + xt + xi;
      float av, bv;
      if (mode == 0) {
        float vv = A[(size_t)r*lda + x];
        float vs = ((float)x + 0.5f)*DVf - 8.0f;
        if (mat == 0)      { av = vv * (fmaxf(vs,0.f)*DVf); bv = vv; }
        else if (mat == 1) { av = vv * (fminf(vs,0.f)*DVf); bv = vv; }
        else if (mat == 2) { av = vv * ((vs<0.f)?DVf:0.f); bv = vv; }
        else if (mat == 3) { av = vv * ((vs>0.f)?DVf:0.f); bv = vv; }
        else if (mat == 4) { av = vv; bv = (x>=1)   ? (vv - A[(size_t)r*lda + x-1]) : 0.f; }
        else               { av = vv; bv = (x<NV-1) ? (A[(size_t)r*lda + x+1] - vv) : 0.f; }
      } else if (mode == 1) {
        float vv = A[(size_t)r*lda + x];
        float vs = ((float)x + 0.5f)*DVf - 8.0f;
        float w = (mat==0) ? ((vs<0.f)?DVf:0.f) : ((vs>0.f)?DVf:0.f);
        av = vv*w; bv = vv;
      } else if (mode == 2) {
        av = A[(size_t)r*lda + x];
        const float* Bp = B + (size_t)r*ldb + boff + x;
        bv = (mat==0) ? (Bp[0] - Bp[-1]) : (Bp[1] - Bp[0]);
      } else if (mode == 3) {
        float e = W[e_abs + x] * fac;
        float vv = A[(size_t)r*lda + x];
        av = vv * (((mat==0) ? fmaxf(e,0.f) : fminf(e,0.f)) * DXf);
        bv = vv;
      } else { // mode 4 fused
        if (mat < 2) {
          av = A[(size_t)r*lda + x];
          const float* Bp = B + (size_t)r*ldb + boff + x;
          bv = (mat==0) ? (Bp[0] - Bp[-1]) : (Bp[1] - Bp[0]);
        } else {
          float e = W[e_abs + x] * fac;
          float vv = A[(size_t)r*lda + x];
          av = vv * (((mat==2) ? fmaxf(e,0.f) : fminf(e,0.f)) * DXf);
          bv = vv;
        }
      }
      tA[xi][r] = av; tB[xi][r] = bv;
    }
    __syncthreads();
    for (int xi = 0; xi < TW; ++xi) {
      float a0 = tA[xi][ty*4+0], a1 = tA[xi][ty*4+1], a2 = tA[xi][ty*4+2], a3 = tA[xi][ty*4+3];
      float b0 = tB[xi][tx*4+0], b1 = tB[xi][tx*4+1], b2 = tB[xi][tx*4+2], b3 = tB[xi][tx*4+3];
      acc[0][0]+=a0*b0; acc[0][1]+=a0*b1; acc[0][2]+=a0*b2; acc[0][3]+=a0*b3;
      acc[1][0]+=a1*b0; acc[1][1]+=a1*b1; acc[1][2]+=a1*b2; acc[1][3]+=a1*b3;
      acc[2][0]+=a2*b0; acc[2][1]+=a2*b1; acc[2][2]+=a2*b2; acc[2][3]+=a2*b3;
      acc[3][0]+=a3*b0; acc[3][1]+=a3*b1; acc[3][2]+=a3*b2; acc[3][3]+=a3*b3;
    }
    __syncthreads();
  }
  #pragma unroll
  for (int i = 0; i < 4; ++i)
    #pragma unroll
    for (int j = 0; j < 4; ++j)
      outp[(ty*4+i)*64 + tx*4 + j] = acc[i][j];
}

// gram with fp64 accumulation for QR (A only)
__global__ __launch_bounds__(256) void k_gram_qr(float* W, int a_off, int lda, int aoff,
    int N, int nsplit, int outd_off)
{
  int sp = blockIdx.z, split = blockIdx.x;
  float* base = W + (size_t)sp*SPS;
  const float* A = base + a_off + aoff;
  double* outp = (double*)(base + outd_off) + (size_t)split*4096;
  int chunk = N / nsplit, x0 = split*chunk;
  __shared__ float tA[TW][R+1];
  double acc[4][4] = {};
  int tid = threadIdx.x, ty = tid >> 4, tx = tid & 15;
  for (int xt = 0; xt < chunk; xt += TW) {
    for (int idx = tid; idx < TW*R; idx += 256) {
      int xi = idx & 63, r = idx >> 6;
      tA[xi][r] = A[(size_t)r*lda + x0 + xt + xi];
    }
    __syncthreads();
    for (int xi = 0; xi < TW; ++xi) {
      double a0 = tA[xi][ty*4+0], a1 = tA[xi][ty*4+1], a2 = tA[xi][ty*4+2], a3 = tA[xi][ty*4+3];
      double b0 = tA[xi][tx*4+0], b1 = tA[xi][tx*4+1], b2 = tA[xi][tx*4+2], b3 = tA[xi][tx*4+3];
      acc[0][0]+=a0*b0; acc[0][1]+=a0*b1; acc[0][2]+=a0*b2; acc[0][3]+=a0*b3;
      acc[1][0]+=a1*b0; acc[1][1]+=a1*b1; acc[1][2]+=a1*b2; acc[1][3]+=a1*b3;
      acc[2][0]+=a2*b0; acc[2][1]+=a2*b1; acc[2][2]+=a2*b2; acc[2][3]+=a2*b3;
      acc[3][0]+=a3*b0; acc[3][1]+=a3*b1; acc[3][2]+=a3*b2; acc[3][3]+=a3*b3;
    }
    __syncthreads();
  }
  #pragma unroll
  for (int i = 0; i < 4; ++i)
    #pragma unroll
    for (int j = 0; j < 4; ++j)
      outp[(ty*4+i)*64 + tx*4 + j] = acc[i][j];
}

// parallel reduce of f32 partial mats: grid (nmats, 16, 2); 256-elem slice per block
__global__ __launch_bounds__(256) void k_reduce2(float* W, int src_off, int dst_off, int nsplit)
{
  int sp = blockIdx.z, mat = blockIdx.x;
  int e = blockIdx.y*256 + threadIdx.x;
  float* base = W + (size_t)sp*SPS;
  const float* src = base + src_off + (size_t)mat*nsplit*4096 + e;
  float s = 0;
  for (int k = 0; k < nsplit; ++k) s += src[(size_t)k*4096];
  base[dst_off + (size_t)mat*4096 + e] = s;
}

// parallel reduce of f64 QR gram partials: grid (16, 1, 2); 256-elem slice per block
__global__ __launch_bounds__(256) void k_reduced(float* W, int src_off, int dst_off, int nsplit)
{
  int sp = blockIdx.z;
  int e = blockIdx.x*256 + threadIdx.x;
  float* base = W + (size_t)sp*SPS;
  const double* src = (const double*)(base + src_off) + e;
  double s = 0;
  for (int k = 0; k < nsplit; ++k) s += src[(size_t)k*4096];
  ((double*)(base + dst_off))[e] = s;
}

// C[j][x] = alpha*d[j]* sum_r coef(r,j) * B[r][x];  coef = transA? A[j][r] : A[r][j]
// optional mirror store into dout (+ per-species DOUT_SPS) at dmir_off
__global__ __launch_bounds__(256) void k_rr(float* W, int a_off, int transA, int b_off,
    int ldb, int boff, int c_off, int ldc, int coff, int d_off, float alpha,
    float* dout, int dmir_off)
{
  int sp = blockIdx.z;
  float* base = W + (size_t)sp*SPS;
  const float* A = base + a_off;
  const float* B = base + b_off + boff;
  float* C = base + c_off + coff;
  float* M = (dmir_off >= 0) ? (dout + (size_t)sp*DOUT_SPS + dmir_off) : nullptr;
  __shared__ float tA[R][R+1];
  __shared__ float dsc[R];
  int tid = threadIdx.x;
  for (int idx = tid; idx < R*R; idx += 256) {
    int r = idx >> 6, j = idx & 63;
    tA[r][j] = transA ? A[j*R + r] : A[idx];
  }
  if (tid < R) dsc[tid] = (d_off >= 0) ? base[d_off + tid] : 1.0f;
  __syncthreads();
  int ty = tid >> 4, tx = tid & 15;
  int x0 = blockIdx.x*64 + tx*4;
  float acc[4][4] = {};
  for (int r = 0; r < R; ++r) {
    float4 bv = *(const float4*)(B + (size_t)r*ldb + x0);
    float a0 = tA[r][ty*4+0], a1 = tA[r][ty*4+1], a2 = tA[r][ty*4+2], a3 = tA[r][ty*4+3];
    acc[0][0]+=a0*bv.x; acc[0][1]+=a0*bv.y; acc[0][2]+=a0*bv.z; acc[0][3]+=a0*bv.w;
    acc[1][0]+=a1*bv.x; acc[1][1]+=a1*bv.y; acc[1][2]+=a1*bv.z; acc[1][3]+=a1*bv.w;
    acc[2][0]+=a2*bv.x; acc[2][1]+=a2*bv.y; acc[2][2]+=a2*bv.z; acc[2][3]+=a2*bv.w;
    acc[3][0]+=a3*bv.x; acc[3][1]+=a3*bv.y; acc[3][2]+=a3*bv.z; acc[3][3]+=a3*bv.w;
  }
  #pragma unroll
  for (int i = 0; i < 4; ++i) {
    int j = ty*4 + i;
    float s = alpha * dsc[j];
    float4 o = make_float4(acc[i][0]*s, acc[i][1]*s, acc[i][2]*s, acc[i][3]*s);
    *(float4*)(C + (size_t)j*ldc + x0) = o;
    if (M) *(float4*)(M + (size_t)j*ldc + x0) = o;
  }
}

// ghosts for 2-ghost K buffer
__global__ __launch_bounds__(256) void k_ghost2(float* W, int k_off)
{
  int sp = blockIdx.z;
  float* base = W + (size_t)sp*SPS;
  float* K = base + k_off;
  int tid = threadIdx.x;
  int j = tid & 63, c = tid >> 6;
  const float* M = base + MATS_OFF + ((c < 2) ? 2 : 3)*4096;
  int dst = (c==0)?2 : (c==1)?3 : (c==2)?(NX+4):(NX+5);
  int src = (c==0)?5 : (c==1)?4 : (c==2)?(NX+3):(NX+2);
  float s = 0;
  for (int m = 0; m < R; ++m) s += M[j*R + m] * K[(size_t)m*NXP + src];
  K[(size_t)j*NXP + dst] = s;
}

// ghosts for 1-ghost K buffer
__global__ __launch_bounds__(128) void k_ghost1(float* W, int k_off, int vm_idx, int vp_idx)
{
  int sp = blockIdx.z;
  float* base = W + (size_t)sp*SPS;
  float* K = base + k_off;
  int tid = threadIdx.x;
  int j = tid & 63, c = tid >> 6;
  const float* M = base + MATS_OFF + ((c==0)? vm_idx : vp_idx)*4096;
  int dst = (c==0)? 3 : (NX+4);
  int src = (c==0)? 4 : (NX+3);
  float s = 0;
  for (int m = 0; m < R; ++m) s += M[j*R + m] * K[(size_t)m*NXP + src];
  K[(size_t)j*NXP + dst] = s;
}

__global__ __launch_bounds__(256) void k_ghostL(float* W)
{
  int sp = blockIdx.z;
  float* base = W + (size_t)sp*SPS;
  for (int idx = threadIdx.x; idx < 512; idx += 256) {
    int which = idx >> 8; int r = (idx >> 2) & 63; int c = idx & 3;
    int col = (c < 2) ? (2 + c) : (NV + 4 + (c - 2));
    (base + (which ? LB_OFF : LA_OFF))[(size_t)r*NVP + col] = 0.f;
  }
}

// fused slope-limited flux divergence + extra term + SSPRK2 combine
__global__ __launch_bounds__(256) void k_flux(float* W, int U_off, int Kx_off, int ldkx,
    int kxoff, int useWin, int P_off, int Mi_off, int A2_off, int B2_off,
    int e_abs, float fac0, float fac1, float dh_inv, int N, int ldp,
    int stage, int orig_off, int out_off)
{
  int sp = blockIdx.z;
  float* base = W + (size_t)sp*SPS;
  const float* U  = base + U_off;
  const float* Kx = base + Kx_off;
  const float* Pm = base + P_off;
  const float* Mm = base + Mi_off;
  const float* Am = base + A2_off;
  const float* Bm = base + B2_off;
  float fac = sp ? fac1 : fac0;
  int x0 = blockIdx.x * 32;
  __shared__ float win[R][37];
  __shared__ float dLt[32][R+1];
  __shared__ float dRt[32][R+1];
  __shared__ float KTt[32][R+1];
  int tid = threadIdx.x;
  for (int idx = tid; idx < R*36; idx += 256) {
    int c = idx % 36, m = idx / 36;
    win[m][c] = U[(size_t)m*ldp + x0 + 2 + c];
  }
  __syncthreads();
  for (int idx = tid; idx < R*32; idx += 256) {
    int xi = idx & 31, m = idx >> 5;
    float u0 = win[m][xi], u1 = win[m][xi+1], u2 = win[m][xi+2], u3 = win[m][xi+3], u4 = win[m][xi+4];
    float d01 = u1-u0, d12 = u2-u1, d23 = u3-u2, d34 = u4-u3;
    float s1 = mm2(d01,d12), s2 = mm2(d12,d23), s3 = mm2(d23,d34);
    dLt[xi][m] = ((u2 + 0.5f*s2) - (u1 + 0.5f*s1)) * dh_inv;
    dRt[xi][m] = ((u3 - 0.5f*s3) - (u2 - 0.5f*s2)) * dh_inv;
    KTt[xi][m] = useWin ? u2 : Kx[(size_t)m*ldkx + kxoff + x0 + xi];
  }
  __syncthreads();
  int ty = tid >> 4, tx = tid & 15;
  int j0 = ty*4;
  float aP[4][2] = {}, aM[4][2] = {}, aA[4][2] = {}, aB[4][2] = {};
  for (int m = 0; m < R; ++m) {
    float dl0 = dLt[tx*2][m],   dl1 = dLt[tx*2+1][m];
    float dr0 = dRt[tx*2][m],   dr1 = dRt[tx*2+1][m];
    float kt0 = KTt[tx*2][m],   kt1 = KTt[tx*2+1][m];
    #pragma unroll
    for (int i = 0; i < 4; ++i) {
      float p = Pm[(j0+i)*R + m], q = Mm[(j0+i)*R + m];
      float a = Am[(j0+i)*R + m], b = Bm[(j0+i)*R + m];
      aP[i][0] += p*dl0; aP[i][1] += p*dl1;
      aM[i][0] += q*dr0; aM[i][1] += q*dr1;
      aA[i][0] += a*kt0; aA[i][1] += a*kt1;
      aB[i][0] += b*kt0; aB[i][1] += b*kt1;
    }
  }
  const float* orig = base + orig_off;
  float* out = base + out_off;
  for (int xx = 0; xx < 2; ++xx) {
    int x = x0 + tx*2 + xx;
    float w1, w2;
    if (e_abs >= 0) { float e = W[e_abs + x]; w1 = fac*fmaxf(e,0.f); w2 = fac*fminf(e,0.f); }
    else { float vs = ((float)x + 0.5f)*DVf - 8.0f; w1 = fmaxf(vs,0.f); w2 = fminf(vs,0.f); }
    #pragma unroll
    for (int i = 0; i < 4; ++i) {
      int j = j0 + i;
      float rhs = -(aP[i][xx] + aM[i][xx] + w1*aA[i][xx] + w2*aB[i][xx]);
      float uval = win[j][tx*2 + xx + 2];
      float res;
      if (stage == 1) res = uval + DTf*rhs;
      else res = 0.5f*(orig[(size_t)j*ldp + 4 + x] + uval + DTf*rhs);
      out[(size_t)j*ldp + 4 + x] = res;
    }
  }
}

// CholeskyQR1 tail, 256 threads (4-wave work split — R4 structure):
// Gaussian elimination (1 barrier/step) + normalize -> R; blocked tri-inverse -> Rinv;
// T = A_top@Rinv (fp64); LAPACK sign chain -> D; S_out = D*R*sscale (+ mirror).
__global__ __launch_bounds__(256) void k_cholA(float* W, int gd_off,
    int a_off, int lda, int aoff, int sout_off, float sscale,
    float* dout, int dmir_off)
{
  int sp = blockIdx.z;
  float* base = W + (size_t)sp*SPS;
  const double* GD = (const double*)(base + gd_off);
  const float* A = base + a_off + aoff;
  float* Rinv = base + R1IF_OFF;
  __shared__ double G[R][R+1];
  __shared__ double Wi[R][R+1];
  __shared__ double T[R][R+1];
  __shared__ float  As[R][R+1];
  __shared__ double Pb[32][33];
  __shared__ double red[4][R];
  __shared__ double dinv[R];
  __shared__ double dsh[R];
  int tid = threadIdx.x;
  int j = tid & 63, q = tid >> 6;
  for (int e = tid; e < 4096; e += 256) {
    G[e>>6][e&63] = GD[e];
    As[e>>6][e&63] = A[(size_t)(e>>6)*lda + (e&63)];
  }
  __syncthreads();
  // ---- Gaussian elimination, ONE barrier per step (reads touch only row k) ----
  for (int k = 0; k < R; ++k) {
    if (j > k) {
      double gkj = G[k][j] / G[k][k];
      for (int i = k+1+q; i <= j; i += 4) G[i][j] -= G[k][i]*gkj;
    }
    __syncthreads();
  }
  // ---- normalize: R[i][j] = G[i][j] * rsqrt(G[i][i]) ; dinv[i] = 1/R[i][i] ----
  if (tid < R) dinv[tid] = 1.0 / sqrt(G[tid][tid]);
  __syncthreads();
  for (int i = q; i <= j; i += 4) G[i][j] *= dinv[i];
  __syncthreads();
  // ---- blocked tri-inverse: two 32x32 diagonal blocks in parallel ----
  if (q == 0) Wi[j][j] = dinv[j];
  __syncthreads();
  int blo = j & 32;
  for (int t = 1; t < 32; ++t) {
    int i = j - t;
    double s = 0;
    if (i >= blo) {
      for (int m = i+1+q; m <= j; m += 4) s += G[i][m]*Wi[m][j];
    }
    red[q][j] = s;
    __syncthreads();
    if (q == 0 && i >= blo)
      Wi[i][j] = -(red[0][j]+red[1][j]+red[2][j]+red[3][j]) * dinv[i];
    __syncthreads();
  }
  // P = R12 * W22
  for (int u = 0; u < 4; ++u) {
    int e = tid + 256*u;
    int m = e >> 5, jj = 32 + (e & 31);
    double s = 0;
    for (int k2 = 32; k2 <= jj; ++k2) s += G[m][k2]*Wi[k2][jj];
    Pb[m][jj-32] = s;
  }
  __syncthreads();
  // W12 = -W11 * P
  for (int u = 0; u < 4; ++u) {
    int e = tid + 256*u;
    int i = e >> 5, jj = 32 + (e & 31);
    double s = 0;
    for (int m = i; m < 32; ++m) s += Wi[i][m]*Pb[m][jj-32];
    Wi[i][jj] = -s;
  }
  __syncthreads();
  // Rinv f32 out (for k_rr)
  for (int e = tid; e < 4096; e += 256) {
    int i = e>>6, jj = e&63;
    Rinv[e] = (i<=jj) ? (float)Wi[i][jj] : 0.0f;
  }
  // T[x][j] = sum_m Wi[m][j] * As[m][x]   (top block of Q_pos, fp64)
  for (int x = q; x < R; x += 4) {
    double s = 0;
    for (int m = 0; m <= j; ++m) s += Wi[m][j]*(double)As[m][x];
    T[x][j] = s;
  }
  __syncthreads();
  // ---- LAPACK Householder sign chain on exact-orthonormal top block ----
  for (int k = 0; k < R; ++k) {
    double tkk = T[k][k];
    double d = (tkk >= 0.0) ? -1.0 : 1.0;
    if (tid == k) dsh[k] = d;
    if (j > k) {
      double c = d * T[k][j] / (1.0 + fabs(tkk));
      for (int m = k+1+q; m < R; m += 4) T[m][j] += c * T[m][k];
    }
    __syncthreads();
  }
  if (tid < 64) base[D_OFF + tid] = (float)dsh[tid];
  float* mir = (dmir_off >= 0) ? (dout + (size_t)sp*DOUT_SPS + dmir_off) : nullptr;
  for (int e = tid; e < 4096; e += 256) {
    int i = e >> 6, jj = e & 63;
    float v = (i <= jj) ? (float)(dsh[i] * G[i][jj] * (double)sscale) : 0.0f;
    base[sout_off + e] = v;
    if (mir) mir[e] = v;
  }
}

// S-step small combine from pre-reduced mats at SM_OFF
__global__ __launch_bounds__(256) void k_sstep(float* W, int stage)
{
  int sp = blockIdx.x;
  float* base = W + (size_t)sp*SPS;
  float fac = sp ? FAC_I : FAC_E;
  __shared__ float Ab[4096], Bb[4096], Cb[4096];
  int tid = threadIdx.x, ty = tid >> 4, tx = tid & 15;
  for (int e = tid; e < 4096; e += 256) {
    Ab[e] = base[SM_OFF + e];            // KL
    Bb[e] = base[SM_OFF + 4096 + e];     // KR
  }
  __syncthreads();
  const float* vpm = base + MATS_OFF + 0*4096;
  const float* vmm = base + MATS_OFF + 1*4096;
  const float* vlm = base + MATS_OFF + 4*4096;
  const float* vrm = base + MATS_OFF + 5*4096;
  float accV[4][4] = {}, accE[4][4] = {};
  for (int m = 0; m < R; ++m) {
    float kl[4], kr[4], vpj[4], vmj[4];
    #pragma unroll
    for (int i = 0; i < 4; ++i) { kl[i] = Ab[(ty*4+i)*64+m]; kr[i] = Bb[(ty*4+i)*64+m]; }
    #pragma unroll
    for (int j = 0; j < 4; ++j) { vpj[j] = vpm[(tx*4+j)*64+m]; vmj[j] = vmm[(tx*4+j)*64+m]; }
    #pragma unroll
    for (int i = 0; i < 4; ++i)
      #pragma unroll
      for (int j = 0; j < 4; ++j)
        accV[i][j] += kl[i]*vpj[j] + kr[i]*vmj[j];
  }
  __syncthreads();
  const float* Sin = base + ((stage==1)? S_OFF : S1_OFF);
  for (int e = tid; e < 4096; e += 256) {
    Cb[e] = Sin[e];
    Ab[e] = base[SM_OFF + 2*4096 + e];   // Ep_mat
  }
  __syncthreads();
  float t1[4][4] = {};
  for (int m = 0; m < R; ++m) {
    float ar[4], cj[4];
    #pragma unroll
    for (int i = 0; i < 4; ++i) ar[i] = Ab[(ty*4+i)*64+m];
    #pragma unroll
    for (int j = 0; j < 4; ++j) cj[j] = Cb[m*64 + tx*4+j];
    #pragma unroll
    for (int i = 0; i < 4; ++i)
      #pragma unroll
      for (int j = 0; j < 4; ++j) t1[i][j] += ar[i]*cj[j];
  }
  __syncthreads();
  #pragma unroll
  for (int i = 0; i < 4; ++i)
    #pragma unroll
    for (int j = 0; j < 4; ++j) Bb[(ty*4+i)*64 + tx*4+j] = t1[i][j];
  __syncthreads();
  for (int m = 0; m < R; ++m) {
    float ar[4], vj[4];
    #pragma unroll
    for (int i = 0; i < 4; ++i) ar[i] = Bb[(ty*4+i)*64+m];
    #pragma unroll
    for (int j = 0; j < 4; ++j) vj[j] = vlm[(tx*4+j)*64+m];
    #pragma unroll
    for (int i = 0; i < 4; ++i)
      #pragma unroll
      for (int j = 0; j < 4; ++j) accE[i][j] += ar[i]*vj[j];
  }
  __syncthreads();
  for (int e = tid; e < 4096; e += 256) Ab[e] = base[SM_OFF + 3*4096 + e];  // Em_mat
  __syncthreads();
  float t2[4][4] = {};
  for (int m = 0; m < R; ++m) {
    float ar[4], cj[4];
    #pragma unroll
    for (int i = 0; i < 4; ++i) ar[i] = Ab[(ty*4+i)*64+m];
    #pragma unroll
    for (int j = 0; j < 4; ++j) cj[j] = Cb[m*64 + tx*4+j];
    #pragma unroll
    for (int i = 0; i < 4; ++i)
      #pragma unroll
      for (int j = 0; j < 4; ++j) t2[i][j] += ar[i]*cj[j];
  }
  __syncthreads();
  #pragma unroll
  for (int i = 0; i < 4; ++i)
    #pragma unroll
    for (int j = 0; j < 4; ++j) Bb[(ty*4+i)*64 + tx*4+j] = t2[i][j];
  __syncthreads();
  for (int m = 0; m < R; ++m) {
    float ar[4], vj[4];
    #pragma unroll
    for (int i = 0; i < 4; ++i) ar[i] = Bb[(ty*4+i)*64+m];
    #pragma unroll
    for (int j = 0; j < 4; ++j) vj[j] = vrm[(tx*4+j)*64+m];
    #pragma unroll
    for (int i = 0; i < 4; ++i)
      #pragma unroll
      for (int j = 0; j < 4; ++j) accE[i][j] += ar[i]*vj[j];
  }
  #pragma unroll
  for (int i = 0; i < 4; ++i)
    #pragma unroll
    for (int j = 0; j < 4; ++j) {
      int e = (ty*4+i)*64 + tx*4+j;
      float rhs = accV[i][j] + fac*accE[i][j];
      if (stage == 1) base[S1_OFF + e] = base[S_OFF + e] + DTf*rhs;
      else base[S_OFF + e] = 0.5f*(base[S_OFF + e] + base[S1_OFF + e] + DTf*rhs);
    }
}

// charge moments: c = Z * S @ (V @ 1 * DV)
__global__ __launch_bounds__(256) void k_csolve(float* W)
{
  int sp = blockIdx.x;
  float* base = W + (size_t)sp*SPS;
  const float* V = base + V_OFF;
  const float* S = base + S_OFF;
  __shared__ float red[R][4];
  __shared__ float mass[R];
  int tid = threadIdx.x;
  int r = tid >> 2, q = tid & 3;
  float s = 0;
  for (int v = q; v < NV; v += 4) s += V[(size_t)r*NV + v];
  red[r][q] = s;
  __syncthreads();
  if (tid < R) mass[tid] = (red[tid][0]+red[tid][1]+red[tid][2]+red[tid][3]) * DVf;
  __syncthreads();
  if (tid < R) {
    float c = 0;
    for (int j = 0; j < R; ++j) c += S[tid*R + j] * mass[j];
    W[C_OFF + sp*R + tid] = c * (sp ? ZI_F : ZE_F);
  }
}

__global__ __launch_bounds__(256) void k_rho(float* W)
{
  int x = blockIdx.x*256 + threadIdx.x;
  float s = 0;
  for (int r = 0; r < R; ++r) s += W[X_OFF + (size_t)r*NX + x] * W[C_OFF + r];
  for (int r = 0; r < R; ++r) s += W[(size_t)SPS + X_OFF + (size_t)r*NX + x] * W[C_OFF + R + r];
  W[RHO_OFF + x] = s;
}

// -------- FFT: length-128 radix-2 DIT in LDS, 64 threads --------
__device__ inline void fft128fwd(float2* b, int t)
{
  __syncthreads();
  int r0 = (int)(__brev((unsigned)t) >> 25);
  int r1 = (int)(__brev((unsigned)(t+64)) >> 25);
  float2 a0 = b[r0], a1 = b[r1];
  __syncthreads();
  b[t] = a0; b[t+64] = a1;
  for (int s = 1; s <= 7; ++s) {
    __syncthreads();
    int half = 1 << (s-1);
    int jj = t & (half-1);
    int g  = t >> (s-1);
    int pos = (g << s) + jj;
    float ang = -2.0f*PI_F*(float)jj / (float)(1 << s);
    float sn, cs; sincosf(ang, &sn, &cs);
    float2 u = b[pos], wv = b[pos+half];
    float2 v = make_float2(wv.x*cs - wv.y*sn, wv.x*sn + wv.y*cs);
    b[pos] = make_float2(u.x+v.x, u.y+v.y);
    b[pos+half] = make_float2(u.x-v.x, u.y-v.y);
  }
}

// pass A: per-n1 length-128 FFT over n2 (stride 128) + four-step twiddle, write transposed
__global__ __launch_bounds__(64) void k_fftA(float* W, int rin_off, int cin_off, int out_off)
{
  __shared__ float2 bb[128];
  int n1 = blockIdx.x, t = threadIdx.x;
  if (rin_off >= 0) {
    const float* rin = W + rin_off;
    bb[t]    = make_float2(rin[n1 + 128*t], 0.f);
    bb[t+64] = make_float2(rin[n1 + 128*(t+64)], 0.f);
  } else {
    const float2* cin = (const float2*)(W + cin_off);
    bb[t] = cin[n1 + 128*t]; bb[t+64] = cin[n1 + 128*(t+64)];
  }
  fft128fwd(bb, t);
  __syncthreads();
  float2* outp = (float2*)(W + out_off);
  for (int kk = 0; kk < 2; ++kk) {
    int k2 = t + 64*kk;
    float ang = -2.0f*PI_F*(float)(n1*k2) * (1.0f/16384.0f);
    float sn, cs; sincosf(ang, &sn, &cs);
    float2 v = bb[k2];
    outp[k2*128 + n1] = make_float2(v.x*cs - v.y*sn, v.x*sn + v.y*cs);
  }
}

// pass B: per-k2 FFT over n1; spectral scale 1/(ik); write conj(H) in natural order
__global__ __launch_bounds__(64) void k_fftB(float* W, int in_off, int out_off)
{
  __shared__ float2 bb[128];
  int k2 = blockIdx.x, t = threadIdx.x;
  const float2* in = (const float2*)(W + in_off);
  bb[t] = in[k2*128 + t]; bb[t+64] = in[k2*128 + t + 64];
  fft128fwd(bb, t);
  __syncthreads();
  float2* outp = (float2*)(W + out_off);
  for (int kk = 0; kk < 2; ++kk) {
    int k1 = t + 64*kk;
    int j = k2 + 128*k1;
    float2 X = bb[k1];
    float2 Hc;
    if (j == 0) Hc = make_float2(0.f, 0.f);
    else {
      float kphys = PI_F * (float)((j < 8192) ? j : (j - 16384));
      Hc = make_float2(X.y / kphys, X.x / kphys);   // conj(rho_hat/(i k))
    }
    outp[j] = Hc;
  }
}

// pass D: final FFT pass, take Re()/N -> E
__global__ __launch_bounds__(64) void k_fftD(float* W, int in_off, int e_off)
{
  __shared__ float2 bb[128];
  int k2 = blockIdx.x, t = threadIdx.x;
  const float2* in = (const float2*)(W + in_off);
  bb[t] = in[k2*128 + t]; bb[t+64] = in[k2*128 + t + 64];
  fft128fwd(bb, t);
  __syncthreads();
  for (int kk = 0; kk < 2; ++kk) {
    int k1 = t + 64*kk;
    W[e_off + k2 + 128*k1] = bb[k1].x * (1.0f/16384.0f);
  }
}

// ----------------------------------------------------------------------------
extern "C" void kernel_launch(void* const* d_in, const int* in_sizes, int n_in,
                              void* d_out, int out_size, void* d_ws, size_t ws_size,
                              hipStream_t stream)
{
  float* W = (float*)d_ws;
  float* outp = (float*)d_out;
  const size_t FB = sizeof(float);
  // inputs: Xe, Se, Ve, Xi, Si, Vi
  hipMemcpyAsync(W + X_OFF, d_in[0], FB*(size_t)R*NX, hipMemcpyDeviceToDevice, stream);
  hipMemcpyAsync(W + S_OFF, d_in[1], FB*(size_t)R*R,  hipMemcpyDeviceToDevice, stream);
  hipMemcpyAsync(W + V_OFF, d_in[2], FB*(size_t)R*NV, hipMemcpyDeviceToDevice, stream);
  hipMemcpyAsync(W + (size_t)SPS + X_OFF, d_in[3], FB*(size_t)R*NX, hipMemcpyDeviceToDevice, stream);
  hipMemcpyAsync(W + (size_t)SPS + S_OFF, d_in[4], FB*(size_t)R*R,  hipMemcpyDeviceToDevice, stream);
  hipMemcpyAsync(W + (size_t)SPS + V_OFF, d_in[5], FB*(size_t)R*NV, hipMemcpyDeviceToDevice, stream);

  // V-derived matrices (vplus,vminus,Vm,Vp,Vl,Vr)
  k_gram<<<dim3(SPLIT_VM,6,2),256,0,stream>>>(W, 0, V_OFF, NV, V_OFF, NV, 0, -1, 0.f,0.f, PART_OFF, NV, SPLIT_VM);
  k_reduce2<<<dim3(6,16,2),256,0,stream>>>(W, PART_OFF, MATS_OFF, SPLIT_VM);

  auto poisson = [&]() {
    k_csolve<<<dim3(2),256,0,stream>>>(W);
    k_rho<<<dim3(NX/256),256,0,stream>>>(W);
    k_fftA<<<dim3(128),64,0,stream>>>(W, RHO_OFF, -1, FFT1_OFF);
    k_fftB<<<dim3(128),64,0,stream>>>(W, FFT1_OFF, FFT2_OFF);
    k_fftA<<<dim3(128),64,0,stream>>>(W, -1, FFT2_OFF, FFT1_OFF);
    k_fftD<<<dim3(128),64,0,stream>>>(W, FFT1_OFF, E_OFF);
  };

  // CholeskyQR1 + LAPACK-sign emulation; optional d_out mirrors
  auto qr = [&](int a_off, int lda, int aoff, int N_, int nsplit,
                int sout_off, float sscale, int xout_off, int xout_ld, float inv_s,
                int smir, int xmir) {
    k_gram_qr<<<dim3(nsplit,1,2),256,0,stream>>>(W, a_off, lda, aoff, N_, nsplit, PARTQR_OFF);
    k_reduced<<<dim3(16,1,2),256,0,stream>>>(W, PARTQR_OFF, GD_OFF, nsplit);
    k_cholA<<<dim3(1,1,2),256,0,stream>>>(W, GD_OFF, a_off, lda, aoff, sout_off, sscale, outp, smir);
    k_rr<<<dim3(N_/64,1,2),256,0,stream>>>(W, R1IF_OFF, 0, a_off, lda, aoff, xout_off, xout_ld, 0, D_OFF, inv_s, outp, xmir);
  };

  // ---------- Poisson #1 + K-step ----------
  poisson();
  k_rr<<<dim3(NX/64,1,2),256,0,stream>>>(W, S_OFF, 0, X_OFF, NX, 0, KA_OFF, NXP, 4, -1, 1.0f, nullptr, -1);
  k_ghost2<<<dim3(1,1,2),256,0,stream>>>(W, KA_OFF);
  k_flux<<<dim3(NX/32,1,2),256,0,stream>>>(W, KA_OFF, KA_OFF, NXP, 4, 1,
      MATS_OFF+0*4096, MATS_OFF+1*4096, MATS_OFF+4*4096, MATS_OFF+5*4096,
      E_OFF, FAC_E, FAC_I, 1.0f/DXf, NX, NXP, 1, 0, KB_OFF);
  k_ghost2<<<dim3(1,1,2),256,0,stream>>>(W, KB_OFF);
  k_flux<<<dim3(NX/32,1,2),256,0,stream>>>(W, KB_OFF, KB_OFF, NXP, 4, 1,
      MATS_OFF+0*4096, MATS_OFF+1*4096, MATS_OFF+4*4096, MATS_OFF+5*4096,
      E_OFF, FAC_E, FAC_I, 1.0f/DXf, NX, NXP, 2, KA_OFF, KA_OFF);
  qr(KA_OFF, NXP, 4, NX, SPLIT_QRX, S_OFF, SQRT_DXf, X_OFF, NX, ISQRT_DXf, -1, DOUT_X);

  // ---------- Poisson #2 + S-step ----------
  poisson();
  auto sstep_eval = [&](int stage) {
    int sin = (stage==1) ? S_OFF : S1_OFF;
    k_rr<<<dim3(NX/64,1,2),256,0,stream>>>(W, sin, 0, X_OFF, NX, 0, KA_OFF, NXP, 4, -1, 1.0f, nullptr, -1);
    k_ghost1<<<dim3(1,1,2),128,0,stream>>>(W, KA_OFF, 2, 3);
    k_gram<<<dim3(SPLIT_X,4,2),256,0,stream>>>(W, 4, X_OFF, NX, KA_OFF, NXP, 4, E_OFF, 1.0f, 1.0f, PART_OFF, NX, SPLIT_X);
    k_reduce2<<<dim3(4,16,2),256,0,stream>>>(W, PART_OFF, SM_OFF, SPLIT_X);
    k_sstep<<<dim3(2),256,0,stream>>>(W, stage);
  };
  sstep_eval(1);
  sstep_eval(2);

  // ---------- Poisson #3 + L-step ----------
  poisson();
  k_rr<<<dim3(NV/64,1,2),256,0,stream>>>(W, S_OFF, 1, V_OFF, NV, 0, LA_OFF, NVP, 4, -1, 1.0f, nullptr, -1);
  k_ghostL<<<dim3(1,1,2),256,0,stream>>>(W);
  auto leval = [&](int Lsrc, int stage, int Ldst, int Lorig) {
    qr(Lsrc, NVP, 4, NV, SPLIT_QRV, SQ_OFF, SQRT_DVf, VQ_OFF, NV, ISQRT_DVf, -1, -1);
    k_gram<<<dim3(SPLIT_VM,2,2),256,0,stream>>>(W, 1, VQ_OFF, NV, VQ_OFF, NV, 0, -1, 0.f,0.f, PART_OFF, NV, SPLIT_VM);
    k_reduce2<<<dim3(2,16,2),256,0,stream>>>(W, PART_OFF, MATS_OFF + 6*4096, SPLIT_VM);
    k_rr<<<dim3(NX/64,1,2),256,0,stream>>>(W, SQ_OFF, 0, X_OFF, NX, 0, KA_OFF, NXP, 4, -1, 1.0f, nullptr, -1);
    k_ghost1<<<dim3(1,1,2),128,0,stream>>>(W, KA_OFF, 6, 7);
    k_gram<<<dim3(SPLIT_X,4,2),256,0,stream>>>(W, 4, X_OFF, NX, KA_OFF, NXP, 4, E_OFF, FAC_E, FAC_I, PART_OFF, NX, SPLIT_X);
    k_reduce2<<<dim3(4,16,2),256,0,stream>>>(W, PART_OFF, SM_OFF, SPLIT_X);
    k_flux<<<dim3(NV/32,1,2),256,0,stream>>>(W, Lsrc, VQ_OFF, NV, 0, 0,
        SM_OFF+2*4096, SM_OFF+3*4096, SM_OFF+0*4096, SM_OFF+1*4096,
        -1, 0.f, 0.f, 1.0f/DVf, NV, NVP, stage, Lorig, Ldst);
  };
  leval(LA_OFF, 1, LB_OFF, 0);
  leval(LB_OFF, 2, LA_OFF, LA_OFF);
  qr(LA_OFF, NVP, 4, NV, SPLIT_QRV, S_OFF, SQRT_DVf, V_OFF, NV, ISQRT_DVf, DOUT_S, DOUT_V);

  (void)in_sizes; (void)n_in; (void)out_size; (void)ws_size;
}

// Round 7
// 1415.771 us; speedup vs baseline: 1.7720x; 1.2312x over previous
//
#include <hip/hip_runtime.h>

#define R 64
#define NX 16384
#define NV 2048
#define NXP (NX+8)
#define NVP (NV+8)
#define TW 64
#define SPLIT_VM 8
#define SPLIT_X 64
#define SPLIT_QRX 128
#define SPLIT_QRV 32

#define DXf 1.220703125e-4f
#define DVf 0.0078125f
#define DTf 0.001f
#define PI_F 3.14159265358979323846f
#define FAC_E (-1.0f)
#define FAC_I (0.01f)
#define ZE_F (-1.0f)
#define ZI_F (1.0f)
#define SQRT_DXf 0.011048543456039806f
#define SQRT_DVf 0.08838834764831845f
#define ISQRT_DXf 90.50966799187808f
#define ISQRT_DVf 11.313708498984761f

// ---------------- workspace layout (float offsets), per-species stride SPS ----
#define X_OFF 0
#define V_OFF 1048576
#define S_OFF 1179648
#define S1_OFF 1183744
#define SQ_OFF 1187840
#define D_OFF 1191936
#define MATS_OFF 1196032      /* 8 mats: vplus,vminus,Vm,Vp,Vl,Vr,Vmq,Vpq */
#define SM_OFF 1228800        /* KL,KR,EpM,EmM finals */
#define GLR_OFF 1245184       /* GL, GR (2 x 4096 f32) */
#define R1IF_OFF 1269760      /* f32 Rinv */
#define KA_OFF 1277952        /* 64 x NXP padded */
#define KB_OFF 2327040        /* 64 x NXP padded ; L-phase aliases below */
#define LA_OFF KB_OFF
#define LB_OFF (KB_OFF+131584)
#define VQ_OFF (KB_OFF+394240)
#define PART_OFF 3376128      /* f32 partials; aliased as f64 QR partials (max 128x4096 dbl = 4MB) */
#define PARTQR_OFF PART_OFF
#define GD_OFF 4686848        /* reduced f64 gram: 4096 doubles */
#define SPS 4695040
// shared region
#define RHO_OFF 9390080
#define E_OFF 9406464
#define C_OFF 9422848
#define FFT1_OFF 9426944
#define FFT2_OFF 9459712
// d_out per-species layout
#define DOUT_SPS 1183744
#define DOUT_X 0
#define DOUT_S 1048576
#define DOUT_V 1052672

__device__ __forceinline__ float mm2(float a, float b) {
    return (a*b > 0.0f) ? ((fabsf(a) < fabsf(b)) ? a : b) : 0.0f;
}

// ---------------- generic weighted gram: C[a][b] = sum_x av(a,x)*bv(b,x) ------
// mode 0: 6 V-matrices   mode 1: Vm/Vp masks from Vq
// mode 3: Ep_mat/Em_mat (weight fac*E, *DX)   mode 5: GL/GR boundary-adjusted X-diff grams
__global__ __launch_bounds__(256) void k_gram(float* W, int mode, int a_off, int lda,
    int e_abs, float fac0, float fac1, int out_off, int N, int nsplit)
{
  int sp = blockIdx.z, mat = blockIdx.y, split = blockIdx.x;
  float* base = W + (size_t)sp*SPS;
  const float* A = base + a_off;
  float fac = sp ? fac1 : fac0;
  float* outp = base + out_off + (size_t)(mat*nsplit + split)*4096;
  int chunk = N / nsplit;
  int xb0 = split * chunk;
  __shared__ float tA[TW][R+1], tB[TW][R+1];
  float acc[4][4] = {};
  int tid = threadIdx.x, ty = tid >> 4, tx = tid & 15;
  for (int xt = 0; xt < chunk; xt += TW) {
    for (int idx = tid; idx < TW*R; idx += 256) {
      int xi = idx & 63, r = idx >> 6;
      int x = xb0 + xt + xi;
      float av, bv;
      if (mode == 0) {
        float vv = A[(size_t)r*lda + x];
        float vs = ((float)x + 0.5f)*DVf - 8.0f;
        if (mat == 0)      { av = vv * (fmaxf(vs,0.f)*DVf); bv = vv; }
        else if (mat == 1) { av = vv * (fminf(vs,0.f)*DVf); bv = vv; }
        else if (mat == 2) { av = vv * ((vs<0.f)?DVf:0.f); bv = vv; }
        else if (mat == 3) { av = vv * ((vs>0.f)?DVf:0.f); bv = vv; }
        else if (mat == 4) { av = vv; bv = (x>=1)   ? (vv - A[(size_t)r*lda + x-1]) : 0.f; }
        else               { av = vv; bv = (x<NV-1) ? (A[(size_t)r*lda + x+1] - vv) : 0.f; }
      } else if (mode == 1) {
        float vv = A[(size_t)r*lda + x];
        float vs = ((float)x + 0.5f)*DVf - 8.0f;
        float w = (mat==0) ? ((vs<0.f)?DVf:0.f) : ((vs>0.f)?DVf:0.f);
        av = vv*w; bv = vv;
      } else if (mode == 3) {
        float e = W[e_abs + x] * fac;
        float vv = A[(size_t)r*lda + x];
        av = vv * (((mat==0) ? fmaxf(e,0.f) : fminf(e,0.f)) * DXf);
        bv = vv;
      } else { // mode 5: GL (mat0), GR (mat1)
        float vv = A[(size_t)r*lda + x];
        av = vv;
        if (mat == 0) bv = (x>=1)  ? (vv - A[(size_t)r*lda + x-1]) : vv;
        else          bv = (x<N-1) ? (A[(size_t)r*lda + x+1] - vv) : -vv;
      }
      tA[xi][r] = av; tB[xi][r] = bv;
    }
    __syncthreads();
    for (int xi = 0; xi < TW; ++xi) {
      float a0 = tA[xi][ty*4+0], a1 = tA[xi][ty*4+1], a2 = tA[xi][ty*4+2], a3 = tA[xi][ty*4+3];
      float b0 = tB[xi][tx*4+0], b1 = tB[xi][tx*4+1], b2 = tB[xi][tx*4+2], b3 = tB[xi][tx*4+3];
      acc[0][0]+=a0*b0; acc[0][1]+=a0*b1; acc[0][2]+=a0*b2; acc[0][3]+=a0*b3;
      acc[1][0]+=a1*b0; acc[1][1]+=a1*b1; acc[1][2]+=a1*b2; acc[1][3]+=a1*b3;
      acc[2][0]+=a2*b0; acc[2][1]+=a2*b1; acc[2][2]+=a2*b2; acc[2][3]+=a2*b3;
      acc[3][0]+=a3*b0; acc[3][1]+=a3*b1; acc[3][2]+=a3*b2; acc[3][3]+=a3*b3;
    }
    __syncthreads();
  }
  #pragma unroll
  for (int i = 0; i < 4; ++i)
    #pragma unroll
    for (int j = 0; j < 4; ++j)
      outp[(ty*4+i)*64 + tx*4 + j] = acc[i][j];
}

// gram with fp64 accumulation for QR (A only)
__global__ __launch_bounds__(256) void k_gram_qr(float* W, int a_off, int lda, int aoff,
    int N, int nsplit, int outd_off)
{
  int sp = blockIdx.z, split = blockIdx.x;
  float* base = W + (size_t)sp*SPS;
  const float* A = base + a_off + aoff;
  double* outp = (double*)(base + outd_off) + (size_t)split*4096;
  int chunk = N / nsplit, x0 = split*chunk;
  __shared__ float tA[TW][R+1];
  double acc[4][4] = {};
  int tid = threadIdx.x, ty = tid >> 4, tx = tid & 15;
  for (int xt = 0; xt < chunk; xt += TW) {
    for (int idx = tid; idx < TW*R; idx += 256) {
      int xi = idx & 63, r = idx >> 6;
      tA[xi][r] = A[(size_t)r*lda + x0 + xt + xi];
    }
    __syncthreads();
    for (int xi = 0; xi < TW; ++xi) {
      double a0 = tA[xi][ty*4+0], a1 = tA[xi][ty*4+1], a2 = tA[xi][ty*4+2], a3 = tA[xi][ty*4+3];
      double b0 = tA[xi][tx*4+0], b1 = tA[xi][tx*4+1], b2 = tA[xi][tx*4+2], b3 = tA[xi][tx*4+3];
      acc[0][0]+=a0*b0; acc[0][1]+=a0*b1; acc[0][2]+=a0*b2; acc[0][3]+=a0*b3;
      acc[1][0]+=a1*b0; acc[1][1]+=a1*b1; acc[1][2]+=a1*b2; acc[1][3]+=a1*b3;
      acc[2][0]+=a2*b0; acc[2][1]+=a2*b1; acc[2][2]+=a2*b2; acc[2][3]+=a2*b3;
      acc[3][0]+=a3*b0; acc[3][1]+=a3*b1; acc[3][2]+=a3*b2; acc[3][3]+=a3*b3;
    }
    __syncthreads();
  }
  #pragma unroll
  for (int i = 0; i < 4; ++i)
    #pragma unroll
    for (int j = 0; j < 4; ++j)
      outp[(ty*4+i)*64 + tx*4 + j] = acc[i][j];
}

// parallel reduce of f32 partial mats: grid (nmats, 16, 2)
__global__ __launch_bounds__(256) void k_reduce2(float* W, int src_off, int dst_off, int nsplit)
{
  int sp = blockIdx.z, mat = blockIdx.x;
  int e = blockIdx.y*256 + threadIdx.x;
  float* base = W + (size_t)sp*SPS;
  const float* src = base + src_off + (size_t)mat*nsplit*4096 + e;
  float s = 0;
  for (int k = 0; k < nsplit; ++k) s += src[(size_t)k*4096];
  base[dst_off + (size_t)mat*4096 + e] = s;
}

// parallel reduce of f64 QR gram partials: grid (16, 1, 2)
__global__ __launch_bounds__(256) void k_reduced(float* W, int src_off, int dst_off, int nsplit)
{
  int sp = blockIdx.z;
  int e = blockIdx.x*256 + threadIdx.x;
  float* base = W + (size_t)sp*SPS;
  const double* src = (const double*)(base + src_off) + e;
  double s = 0;
  for (int k = 0; k < nsplit; ++k) s += src[(size_t)k*4096];
  ((double*)(base + dst_off))[e] = s;
}

// C[j][x] = alpha*d[j]* sum_r coef(r,j) * B[r][x];  coef = transA? A[j][r] : A[r][j]
__global__ __launch_bounds__(256) void k_rr(float* W, int a_off, int transA, int b_off,
    int ldb, int boff, int c_off, int ldc, int coff, int d_off, float alpha,
    float* dout, int dmir_off)
{
  int sp = blockIdx.z;
  float* base = W + (size_t)sp*SPS;
  const float* A = base + a_off;
  const float* B = base + b_off + boff;
  float* C = base + c_off + coff;
  float* M = (dmir_off >= 0) ? (dout + (size_t)sp*DOUT_SPS + dmir_off) : nullptr;
  __shared__ float tA[R][R+1];
  __shared__ float dsc[R];
  int tid = threadIdx.x;
  for (int idx = tid; idx < R*R; idx += 256) {
    int r = idx >> 6, j = idx & 63;
    tA[r][j] = transA ? A[j*R + r] : A[idx];
  }
  if (tid < R) dsc[tid] = (d_off >= 0) ? base[d_off + tid] : 1.0f;
  __syncthreads();
  int ty = tid >> 4, tx = tid & 15;
  int x0 = blockIdx.x*64 + tx*4;
  float acc[4][4] = {};
  for (int r = 0; r < R; ++r) {
    float4 bv = *(const float4*)(B + (size_t)r*ldb + x0);
    float a0 = tA[r][ty*4+0], a1 = tA[r][ty*4+1], a2 = tA[r][ty*4+2], a3 = tA[r][ty*4+3];
    acc[0][0]+=a0*bv.x; acc[0][1]+=a0*bv.y; acc[0][2]+=a0*bv.z; acc[0][3]+=a0*bv.w;
    acc[1][0]+=a1*bv.x; acc[1][1]+=a1*bv.y; acc[1][2]+=a1*bv.z; acc[1][3]+=a1*bv.w;
    acc[2][0]+=a2*bv.x; acc[2][1]+=a2*bv.y; acc[2][2]+=a2*bv.z; acc[2][3]+=a2*bv.w;
    acc[3][0]+=a3*bv.x; acc[3][1]+=a3*bv.y; acc[3][2]+=a3*bv.z; acc[3][3]+=a3*bv.w;
  }
  #pragma unroll
  for (int i = 0; i < 4; ++i) {
    int j = ty*4 + i;
    float s = alpha * dsc[j];
    float4 o = make_float4(acc[i][0]*s, acc[i][1]*s, acc[i][2]*s, acc[i][3]*s);
    *(float4*)(C + (size_t)j*ldc + x0) = o;
    if (M) *(float4*)(M + (size_t)j*ldc + x0) = o;
  }
}

// ghosts for 2-ghost K buffer
__global__ __launch_bounds__(256) void k_ghost2(float* W, int k_off)
{
  int sp = blockIdx.z;
  float* base = W + (size_t)sp*SPS;
  float* K = base + k_off;
  int tid = threadIdx.x;
  int j = tid & 63, c = tid >> 6;
  const float* M = base + MATS_OFF + ((c < 2) ? 2 : 3)*4096;
  int dst = (c==0)?2 : (c==1)?3 : (c==2)?(NX+4):(NX+5);
  int src = (c==0)?5 : (c==1)?4 : (c==2)?(NX+3):(NX+2);
  float s = 0;
  for (int m = 0; m < R; ++m) s += M[j*R + m] * K[(size_t)m*NXP + src];
  K[(size_t)j*NXP + dst] = s;
}

__global__ __launch_bounds__(256) void k_ghostL(float* W)
{
  int sp = blockIdx.z;
  float* base = W + (size_t)sp*SPS;
  for (int idx = threadIdx.x; idx < 512; idx += 256) {
    int which = idx >> 8; int r = (idx >> 2) & 63; int c = idx & 3;
    int col = (c < 2) ? (2 + c) : (NV + 4 + (c - 2));
    (base + (which ? LB_OFF : LA_OFF))[(size_t)r*NVP + col] = 0.f;
  }
}

// fused slope-limited flux divergence + extra term + SSPRK2 combine
__global__ __launch_bounds__(256) void k_flux(float* W, int U_off, int Kx_off, int ldkx,
    int kxoff, int useWin, int P_off, int Mi_off, int A2_off, int B2_off,
    int e_abs, float fac0, float fac1, float dh_inv, int N, int ldp,
    int stage, int orig_off, int out_off)
{
  int sp = blockIdx.z;
  float* base = W + (size_t)sp*SPS;
  const float* U  = base + U_off;
  const float* Kx = base + Kx_off;
  const float* Pm = base + P_off;
  const float* Mm = base + Mi_off;
  const float* Am = base + A2_off;
  const float* Bm = base + B2_off;
  float fac = sp ? fac1 : fac0;
  int x0 = blockIdx.x * 32;
  __shared__ float win[R][37];
  __shared__ float dLt[32][R+1];
  __shared__ float dRt[32][R+1];
  __shared__ float KTt[32][R+1];
  int tid = threadIdx.x;
  for (int idx = tid; idx < R*36; idx += 256) {
    int c = idx % 36, m = idx / 36;
    win[m][c] = U[(size_t)m*ldp + x0 + 2 + c];
  }
  __syncthreads();
  for (int idx = tid; idx < R*32; idx += 256) {
    int xi = idx & 31, m = idx >> 5;
    float u0 = win[m][xi], u1 = win[m][xi+1], u2 = win[m][xi+2], u3 = win[m][xi+3], u4 = win[m][xi+4];
    float d01 = u1-u0, d12 = u2-u1, d23 = u3-u2, d34 = u4-u3;
    float s1 = mm2(d01,d12), s2 = mm2(d12,d23), s3 = mm2(d23,d34);
    dLt[xi][m] = ((u2 + 0.5f*s2) - (u1 + 0.5f*s1)) * dh_inv;
    dRt[xi][m] = ((u3 - 0.5f*s3) - (u2 - 0.5f*s2)) * dh_inv;
    KTt[xi][m] = useWin ? u2 : Kx[(size_t)m*ldkx + kxoff + x0 + xi];
  }
  __syncthreads();
  int ty = tid >> 4, tx = tid & 15;
  int j0 = ty*4;
  float aP[4][2] = {}, aM[4][2] = {}, aA[4][2] = {}, aB[4][2] = {};
  for (int m = 0; m < R; ++m) {
    float dl0 = dLt[tx*2][m],   dl1 = dLt[tx*2+1][m];
    float dr0 = dRt[tx*2][m],   dr1 = dRt[tx*2+1][m];
    float kt0 = KTt[tx*2][m],   kt1 = KTt[tx*2+1][m];
    #pragma unroll
    for (int i = 0; i < 4; ++i) {
      float p = Pm[(j0+i)*R + m], q = Mm[(j0+i)*R + m];
      float a = Am[(j0+i)*R + m], b = Bm[(j0+i)*R + m];
      aP[i][0] += p*dl0; aP[i][1] += p*dl1;
      aM[i][0] += q*dr0; aM[i][1] += q*dr1;
      aA[i][0] += a*kt0; aA[i][1] += a*kt1;
      aB[i][0] += b*kt0; aB[i][1] += b*kt1;
    }
  }
  const float* orig = base + orig_off;
  float* out = base + out_off;
  for (int xx = 0; xx < 2; ++xx) {
    int x = x0 + tx*2 + xx;
    float w1, w2;
    if (e_abs >= 0) { float e = W[e_abs + x]; w1 = fac*fmaxf(e,0.f); w2 = fac*fminf(e,0.f); }
    else { float vs = ((float)x + 0.5f)*DVf - 8.0f; w1 = fmaxf(vs,0.f); w2 = fminf(vs,0.f); }
    #pragma unroll
    for (int i = 0; i < 4; ++i) {
      int j = j0 + i;
      float rhs = -(aP[i][xx] + aM[i][xx] + w1*aA[i][xx] + w2*aB[i][xx]);
      float uval = win[j][tx*2 + xx + 2];
      float res;
      if (stage == 1) res = uval + DTf*rhs;
      else res = 0.5f*(orig[(size_t)j*ldp + 4 + x] + uval + DTf*rhs);
      out[(size_t)j*ldp + 4 + x] = res;
    }
  }
}

// CholeskyQR1 tail, 512 threads (8-wave work split):
// Gaussian elimination + normalize -> R; blocked tri-inverse -> Rinv;
// T = A_top@Rinv (fp64); LAPACK sign chain -> D; S_out = D*R*sscale (+ mirror).
__global__ __launch_bounds__(512) void k_cholA(float* W, int gd_off,
    int a_off, int lda, int aoff, int sout_off, float sscale,
    float* dout, int dmir_off)
{
  int sp = blockIdx.z;
  float* base = W + (size_t)sp*SPS;
  const double* GD = (const double*)(base + gd_off);
  const float* A = base + a_off + aoff;
  float* Rinv = base + R1IF_OFF;
  __shared__ double G[R][R+1];
  __shared__ double Wi[R][R+1];
  __shared__ double T[R][R+1];
  __shared__ float  As[R][R+1];
  __shared__ double Pb[32][33];
  __shared__ double red[8][R];
  __shared__ double dinv[R];
  __shared__ double dsh[R];
  int tid = threadIdx.x;
  int j = tid & 63, q = tid >> 6;
  for (int e = tid; e < 4096; e += 512) {
    G[e>>6][e&63] = GD[e];
    As[e>>6][e&63] = A[(size_t)(e>>6)*lda + (e&63)];
  }
  __syncthreads();
  // ---- Gaussian elimination, one barrier per step ----
  for (int k = 0; k < R; ++k) {
    if (j > k) {
      double gkj = G[k][j] / G[k][k];
      for (int i = k+1+q; i <= j; i += 8) G[i][j] -= G[k][i]*gkj;
    }
    __syncthreads();
  }
  // ---- normalize rows by rsqrt(diag) ----
  if (tid < R) dinv[tid] = 1.0 / sqrt(G[tid][tid]);
  __syncthreads();
  for (int i = q; i <= j; i += 8) G[i][j] *= dinv[i];
  __syncthreads();
  // ---- blocked tri-inverse: two 32x32 diagonal blocks in parallel ----
  if (q == 0) Wi[j][j] = dinv[j];
  __syncthreads();
  int blo = j & 32;
  for (int t = 1; t < 32; ++t) {
    int i = j - t;
    double s = 0;
    if (i >= blo) {
      for (int m = i+1+q; m <= j; m += 8) s += G[i][m]*Wi[m][j];
    }
    red[q][j] = s;
    __syncthreads();
    if (q == 0 && i >= blo)
      Wi[i][j] = -(red[0][j]+red[1][j]+red[2][j]+red[3][j]
                  +red[4][j]+red[5][j]+red[6][j]+red[7][j]) * dinv[i];
    __syncthreads();
  }
  // P = R12 * W22
  for (int u = 0; u < 2; ++u) {
    int e = tid + 512*u;
    int m = e >> 5, jj = 32 + (e & 31);
    double s = 0;
    for (int k2 = 32; k2 <= jj; ++k2) s += G[m][k2]*Wi[k2][jj];
    Pb[m][jj-32] = s;
  }
  __syncthreads();
  // W12 = -W11 * P
  for (int u = 0; u < 2; ++u) {
    int e = tid + 512*u;
    int i = e >> 5, jj = 32 + (e & 31);
    double s = 0;
    for (int m = i; m < 32; ++m) s += Wi[i][m]*Pb[m][jj-32];
    Wi[i][jj] = -s;
  }
  __syncthreads();
  // Rinv f32 out
  for (int e = tid; e < 4096; e += 512) {
    int i = e>>6, jj = e&63;
    Rinv[e] = (i<=jj) ? (float)Wi[i][jj] : 0.0f;
  }
  // T[x][j] = sum_m Wi[m][j] * As[m][x]
  for (int x = q; x < R; x += 8) {
    double s = 0;
    for (int m = 0; m <= j; ++m) s += Wi[m][j]*(double)As[m][x];
    T[x][j] = s;
  }
  __syncthreads();
  // ---- LAPACK Householder sign chain ----
  for (int k = 0; k < R; ++k) {
    double tkk = T[k][k];
    double d = (tkk >= 0.0) ? -1.0 : 1.0;
    if (tid == k) dsh[k] = d;
    if (j > k) {
      double c = d * T[k][j] / (1.0 + fabs(tkk));
      for (int m = k+1+q; m < R; m += 8) T[m][j] += c * T[m][k];
    }
    __syncthreads();
  }
  if (tid < 64) base[D_OFF + tid] = (float)dsh[tid];
  float* mir = (dmir_off >= 0) ? (dout + (size_t)sp*DOUT_SPS + dmir_off) : nullptr;
  for (int e = tid; e < 4096; e += 512) {
    int i = e >> 6, jj = e & 63;
    float v = (i <= jj) ? (float)(dsh[i] * G[i][jj] * (double)sscale) : 0.0f;
    base[sout_off + e] = v;
    if (mir) mir[e] = v;
  }
}

// KL/KR from R x R algebra: KL = GL@S - x0⊗(Vm(S^T x0)), KR = GR@S + x1⊗(Vp(S^T x1))
__global__ __launch_bounds__(256) void k_klr(float* W, int s_off, int vm_idx, int vp_idx)
{
  int sp = blockIdx.x;
  float* base = W + (size_t)sp*SPS;
  __shared__ float Cb[4096];
  __shared__ float x0s[R], x1s[R], u0[R], u1[R], g0[R], g1[R];
  int tid = threadIdx.x, ty = tid>>4, tx = tid&15;
  const float* Sin = base + s_off;
  for (int e = tid; e < 4096; e += 256) Cb[e] = Sin[e];
  if (tid < R) { x0s[tid] = base[X_OFF + (size_t)tid*NX]; x1s[tid] = base[X_OFF + (size_t)tid*NX + NX-1]; }
  __syncthreads();
  if (tid < R) {
    float s0=0,s1=0;
    for (int m=0;m<R;++m){ float c=Cb[m*64+tid]; s0+=c*x0s[m]; s1+=c*x1s[m]; }
    u0[tid]=s0; u1[tid]=s1;
  }
  __syncthreads();
  if (tid < R) {
    const float* Vm = base + MATS_OFF + vm_idx*4096;
    const float* Vp = base + MATS_OFF + vp_idx*4096;
    float s0=0,s1=0;
    for (int c=0;c<R;++c){ s0+=Vm[tid*64+c]*u0[c]; s1+=Vp[tid*64+c]*u1[c]; }
    g0[tid]=s0; g1[tid]=s1;
  }
  __syncthreads();
  const float* GLg = base + GLR_OFF;
  const float* GRg = base + GLR_OFF + 4096;
  float aKL[4][4]={}, aKR[4][4]={};
  for (int m=0;m<R;++m) {
    float gl[4], gr[4], cj[4];
    #pragma unroll
    for (int i=0;i<4;++i){ gl[i]=GLg[(ty*4+i)*64+m]; gr[i]=GRg[(ty*4+i)*64+m]; }
    #pragma unroll
    for (int j=0;j<4;++j) cj[j]=Cb[m*64+tx*4+j];
    #pragma unroll
    for (int i=0;i<4;++i)
      #pragma unroll
      for (int j=0;j<4;++j){ aKL[i][j]+=gl[i]*cj[j]; aKR[i][j]+=gr[i]*cj[j]; }
  }
  #pragma unroll
  for (int i=0;i<4;++i)
    #pragma unroll
    for (int j=0;j<4;++j){
      int e=(ty*4+i)*64+tx*4+j;
      base[SM_OFF+e]      = aKL[i][j] - x0s[ty*4+i]*g0[tx*4+j];
      base[SM_OFF+4096+e] = aKR[i][j] + x1s[ty*4+i]*g1[tx*4+j];
    }
}

// S-step: fused KL/KR (R x R algebra) + rhs + SSPRK2 combine.
// EpM/EmM pre-reduced at SM_OFF+2,3; GL/GR at GLR_OFF; Vm/Vp = MATS 2,3.
__global__ __launch_bounds__(256) void k_sstep(float* W, int stage)
{
  int sp = blockIdx.x;
  float* base = W + (size_t)sp*SPS;
  float fac = sp ? FAC_I : FAC_E;
  __shared__ float Ab[4096], Bb[4096], Cb[4096];
  __shared__ float x0s[R], x1s[R], u0[R], u1[R], g0[R], g1[R];
  int tid = threadIdx.x, ty = tid >> 4, tx = tid & 15;
  const float* Sin = base + ((stage==1)? S_OFF : S1_OFF);
  for (int e = tid; e < 4096; e += 256) Cb[e] = Sin[e];
  if (tid < R) { x0s[tid] = base[X_OFF + (size_t)tid*NX]; x1s[tid] = base[X_OFF + (size_t)tid*NX + NX-1]; }
  __syncthreads();
  if (tid < R) {
    float s0=0,s1=0;
    for (int m=0;m<R;++m){ float c=Cb[m*64+tid]; s0+=c*x0s[m]; s1+=c*x1s[m]; }
    u0[tid]=s0; u1[tid]=s1;
  }
  __syncthreads();
  if (tid < R) {
    const float* Vm = base + MATS_OFF + 2*4096;
    const float* Vp = base + MATS_OFF + 3*4096;
    float s0=0,s1=0;
    for (int c=0;c<R;++c){ s0+=Vm[tid*64+c]*u0[c]; s1+=Vp[tid*64+c]*u1[c]; }
    g0[tid]=s0; g1[tid]=s1;
  }
  __syncthreads();
  {
    const float* GLg = base + GLR_OFF;
    const float* GRg = base + GLR_OFF + 4096;
    float aKL[4][4]={}, aKR[4][4]={};
    for (int m=0;m<R;++m) {
      float gl[4], gr[4], cj[4];
      #pragma unroll
      for (int i=0;i<4;++i){ gl[i]=GLg[(ty*4+i)*64+m]; gr[i]=GRg[(ty*4+i)*64+m]; }
      #pragma unroll
      for (int j=0;j<4;++j) cj[j]=Cb[m*64+tx*4+j];
      #pragma unroll
      for (int i=0;i<4;++i)
        #pragma unroll
        for (int j=0;j<4;++j){ aKL[i][j]+=gl[i]*cj[j]; aKR[i][j]+=gr[i]*cj[j]; }
    }
    #pragma unroll
    for (int i=0;i<4;++i)
      #pragma unroll
      for (int j=0;j<4;++j){
        int e=(ty*4+i)*64+tx*4+j;
        Ab[e] = aKL[i][j] - x0s[ty*4+i]*g0[tx*4+j];
        Bb[e] = aKR[i][j] + x1s[ty*4+i]*g1[tx*4+j];
      }
  }
  __syncthreads();
  const float* vpm = base + MATS_OFF + 0*4096;
  const float* vmm = base + MATS_OFF + 1*4096;
  const float* vlm = base + MATS_OFF + 4*4096;
  const float* vrm = base + MATS_OFF + 5*4096;
  float accV[4][4] = {}, accE[4][4] = {};
  for (int m = 0; m < R; ++m) {
    float kl[4], kr[4], vpj[4], vmj[4];
    #pragma unroll
    for (int i = 0; i < 4; ++i) { kl[i] = Ab[(ty*4+i)*64+m]; kr[i] = Bb[(ty*4+i)*64+m]; }
    #pragma unroll
    for (int j = 0; j < 4; ++j) { vpj[j] = vpm[(tx*4+j)*64+m]; vmj[j] = vmm[(tx*4+j)*64+m]; }
    #pragma unroll
    for (int i = 0; i < 4; ++i)
      #pragma unroll
      for (int j = 0; j < 4; ++j)
        accV[i][j] += kl[i]*vpj[j] + kr[i]*vmj[j];
  }
  __syncthreads();
  for (int e = tid; e < 4096; e += 256) Ab[e] = base[SM_OFF + 2*4096 + e];   // EpM
  __syncthreads();
  float t1[4][4] = {};
  for (int m = 0; m < R; ++m) {
    float ar[4], cj[4];
    #pragma unroll
    for (int i = 0; i < 4; ++i) ar[i] = Ab[(ty*4+i)*64+m];
    #pragma unroll
    for (int j = 0; j < 4; ++j) cj[j] = Cb[m*64 + tx*4+j];
    #pragma unroll
    for (int i = 0; i < 4; ++i)
      #pragma unroll
      for (int j = 0; j < 4; ++j) t1[i][j] += ar[i]*cj[j];
  }
  __syncthreads();
  #pragma unroll
  for (int i = 0; i < 4; ++i)
    #pragma unroll
    for (int j = 0; j < 4; ++j) Bb[(ty*4+i)*64 + tx*4+j] = t1[i][j];
  __syncthreads();
  for (int m = 0; m < R; ++m) {
    float ar[4], vj[4];
    #pragma unroll
    for (int i = 0; i < 4; ++i) ar[i] = Bb[(ty*4+i)*64+m];
    #pragma unroll
    for (int j = 0; j < 4; ++j) vj[j] = vlm[(tx*4+j)*64+m];
    #pragma unroll
    for (int i = 0; i < 4; ++i)
      #pragma unroll
      for (int j = 0; j < 4; ++j) accE[i][j] += ar[i]*vj[j];
  }
  __syncthreads();
  for (int e = tid; e < 4096; e += 256) Ab[e] = base[SM_OFF + 3*4096 + e];  // EmM
  __syncthreads();
  float t2[4][4] = {};
  for (int m = 0; m < R; ++m) {
    float ar[4], cj[4];
    #pragma unroll
    for (int i = 0; i < 4; ++i) ar[i] = Ab[(ty*4+i)*64+m];
    #pragma unroll
    for (int j = 0; j < 4; ++j) cj[j] = Cb[m*64 + tx*4+j];
    #pragma unroll
    for (int i = 0; i < 4; ++i)
      #pragma unroll
      for (int j = 0; j < 4; ++j) t2[i][j] += ar[i]*cj[j];
  }
  __syncthreads();
  #pragma unroll
  for (int i = 0; i < 4; ++i)
    #pragma unroll
    for (int j = 0; j < 4; ++j) Bb[(ty*4+i)*64 + tx*4+j] = t2[i][j];
  __syncthreads();
  for (int m = 0; m < R; ++m) {
    float ar[4], vj[4];
    #pragma unroll
    for (int i = 0; i < 4; ++i) ar[i] = Bb[(ty*4+i)*64+m];
    #pragma unroll
    for (int j = 0; j < 4; ++j) vj[j] = vrm[(tx*4+j)*64+m];
    #pragma unroll
    for (int i = 0; i < 4; ++i)
      #pragma unroll
      for (int j = 0; j < 4; ++j) accE[i][j] += ar[i]*vj[j];
  }
  #pragma unroll
  for (int i = 0; i < 4; ++i)
    #pragma unroll
    for (int j = 0; j < 4; ++j) {
      int e = (ty*4+i)*64 + tx*4+j;
      float rhs = accV[i][j] + fac*accE[i][j];
      if (stage == 1) base[S1_OFF + e] = base[S_OFF + e] + DTf*rhs;
      else base[S_OFF + e] = 0.5f*(base[S_OFF + e] + base[S1_OFF + e] + DTf*rhs);
    }
}

// charge moments: c = Z * S @ (V @ 1 * DV)
__global__ __launch_bounds__(256) void k_csolve(float* W)
{
  int sp = blockIdx.x;
  float* base = W + (size_t)sp*SPS;
  const float* V = base + V_OFF;
  const float* S = base + S_OFF;
  __shared__ float red[R][4];
  __shared__ float mass[R];
  int tid = threadIdx.x;
  int r = tid >> 2, q = tid & 3;
  float s = 0;
  for (int v = q; v < NV; v += 4) s += V[(size_t)r*NV + v];
  red[r][q] = s;
  __syncthreads();
  if (tid < R) mass[tid] = (red[tid][0]+red[tid][1]+red[tid][2]+red[tid][3]) * DVf;
  __syncthreads();
  if (tid < R) {
    float c = 0;
    for (int j = 0; j < R; ++j) c += S[tid*R + j] * mass[j];
    W[C_OFF + sp*R + tid] = c * (sp ? ZI_F : ZE_F);
  }
}

__global__ __launch_bounds__(256) void k_rho(float* W)
{
  int x = blockIdx.x*256 + threadIdx.x;
  float s = 0;
  for (int r = 0; r < R; ++r) s += W[X_OFF + (size_t)r*NX + x] * W[C_OFF + r];
  for (int r = 0; r < R; ++r) s += W[(size_t)SPS + X_OFF + (size_t)r*NX + x] * W[C_OFF + R + r];
  W[RHO_OFF + x] = s;
}

// -------- FFT: length-128 radix-2 DIT in LDS, 64 threads --------
__device__ inline void fft128fwd(float2* b, int t)
{
  __syncthreads();
  int r0 = (int)(__brev((unsigned)t) >> 25);
  int r1 = (int)(__brev((unsigned)(t+64)) >> 25);
  float2 a0 = b[r0], a1 = b[r1];
  __syncthreads();
  b[t] = a0; b[t+64] = a1;
  for (int s = 1; s <= 7; ++s) {
    __syncthreads();
    int half = 1 << (s-1);
    int jj = t & (half-1);
    int g  = t >> (s-1);
    int pos = (g << s) + jj;
    float ang = -2.0f*PI_F*(float)jj / (float)(1 << s);
    float sn, cs; sincosf(ang, &sn, &cs);
    float2 u = b[pos], wv = b[pos+half];
    float2 v = make_float2(wv.x*cs - wv.y*sn, wv.x*sn + wv.y*cs);
    b[pos] = make_float2(u.x+v.x, u.y+v.y);
    b[pos+half] = make_float2(u.x-v.x, u.y-v.y);
  }
}

__global__ __launch_bounds__(64) void k_fftA(float* W, int rin_off, int cin_off, int out_off)
{
  __shared__ float2 bb[128];
  int n1 = blockIdx.x, t = threadIdx.x;
  if (rin_off >= 0) {
    const float* rin = W + rin_off;
    bb[t]    = make_float2(rin[n1 + 128*t], 0.f);
    bb[t+64] = make_float2(rin[n1 + 128*(t+64)], 0.f);
  } else {
    const float2* cin = (const float2*)(W + cin_off);
    bb[t] = cin[n1 + 128*t]; bb[t+64] = cin[n1 + 128*(t+64)];
  }
  fft128fwd(bb, t);
  __syncthreads();
  float2* outp = (float2*)(W + out_off);
  for (int kk = 0; kk < 2; ++kk) {
    int k2 = t + 64*kk;
    float ang = -2.0f*PI_F*(float)(n1*k2) * (1.0f/16384.0f);
    float sn, cs; sincosf(ang, &sn, &cs);
    float2 v = bb[k2];
    outp[k2*128 + n1] = make_float2(v.x*cs - v.y*sn, v.x*sn + v.y*cs);
  }
}

__global__ __launch_bounds__(64) void k_fftB(float* W, int in_off, int out_off)
{
  __shared__ float2 bb[128];
  int k2 = blockIdx.x, t = threadIdx.x;
  const float2* in = (const float2*)(W + in_off);
  bb[t] = in[k2*128 + t]; bb[t+64] = in[k2*128 + t + 64];
  fft128fwd(bb, t);
  __syncthreads();
  float2* outp = (float2*)(W + out_off);
  for (int kk = 0; kk < 2; ++kk) {
    int k1 = t + 64*kk;
    int j = k2 + 128*k1;
    float2 X = bb[k1];
    float2 Hc;
    if (j == 0) Hc = make_float2(0.f, 0.f);
    else {
      float kphys = PI_F * (float)((j < 8192) ? j : (j - 16384));
      Hc = make_float2(X.y / kphys, X.x / kphys);
    }
    outp[j] = Hc;
  }
}

__global__ __launch_bounds__(64) void k_fftD(float* W, int in_off, int e_off)
{
  __shared__ float2 bb[128];
  int k2 = blockIdx.x, t = threadIdx.x;
  const float2* in = (const float2*)(W + in_off);
  bb[t] = in[k2*128 + t]; bb[t+64] = in[k2*128 + t + 64];
  fft128fwd(bb, t);
  __syncthreads();
  for (int kk = 0; kk < 2; ++kk) {
    int k1 = t + 64*kk;
    W[e_off + k2 + 128*k1] = bb[k1].x * (1.0f/16384.0f);
  }
}

// ----------------------------------------------------------------------------
extern "C" void kernel_launch(void* const* d_in, const int* in_sizes, int n_in,
                              void* d_out, int out_size, void* d_ws, size_t ws_size,
                              hipStream_t stream)
{
  float* W = (float*)d_ws;
  float* outp = (float*)d_out;
  const size_t FB = sizeof(float);
  // inputs: Xe, Se, Ve, Xi, Si, Vi
  hipMemcpyAsync(W + X_OFF, d_in[0], FB*(size_t)R*NX, hipMemcpyDeviceToDevice, stream);
  hipMemcpyAsync(W + S_OFF, d_in[1], FB*(size_t)R*R,  hipMemcpyDeviceToDevice, stream);
  hipMemcpyAsync(W + V_OFF, d_in[2], FB*(size_t)R*NV, hipMemcpyDeviceToDevice, stream);
  hipMemcpyAsync(W + (size_t)SPS + X_OFF, d_in[3], FB*(size_t)R*NX, hipMemcpyDeviceToDevice, stream);
  hipMemcpyAsync(W + (size_t)SPS + S_OFF, d_in[4], FB*(size_t)R*R,  hipMemcpyDeviceToDevice, stream);
  hipMemcpyAsync(W + (size_t)SPS + V_OFF, d_in[5], FB*(size_t)R*NV, hipMemcpyDeviceToDevice, stream);

  // V-derived matrices (vplus,vminus,Vm,Vp,Vl,Vr)
  k_gram<<<dim3(SPLIT_VM,6,2),256,0,stream>>>(W, 0, V_OFF, NV, -1, 0.f,0.f, PART_OFF, NV, SPLIT_VM);
  k_reduce2<<<dim3(6,16,2),256,0,stream>>>(W, PART_OFF, MATS_OFF, SPLIT_VM);

  auto poisson = [&]() {
    k_csolve<<<dim3(2),256,0,stream>>>(W);
    k_rho<<<dim3(NX/256),256,0,stream>>>(W);
    k_fftA<<<dim3(128),64,0,stream>>>(W, RHO_OFF, -1, FFT1_OFF);
    k_fftB<<<dim3(128),64,0,stream>>>(W, FFT1_OFF, FFT2_OFF);
    k_fftA<<<dim3(128),64,0,stream>>>(W, -1, FFT2_OFF, FFT1_OFF);
    k_fftD<<<dim3(128),64,0,stream>>>(W, FFT1_OFF, E_OFF);
  };

  // CholeskyQR1 + LAPACK-sign emulation; optional d_out mirrors
  auto qr = [&](int a_off, int lda, int aoff, int N_, int nsplit,
                int sout_off, float sscale, int xout_off, int xout_ld, float inv_s,
                int smir, int xmir) {
    k_gram_qr<<<dim3(nsplit,1,2),256,0,stream>>>(W, a_off, lda, aoff, N_, nsplit, PARTQR_OFF);
    k_reduced<<<dim3(16,1,2),256,0,stream>>>(W, PARTQR_OFF, GD_OFF, nsplit);
    k_cholA<<<dim3(1,1,2),512,0,stream>>>(W, GD_OFF, a_off, lda, aoff, sout_off, sscale, outp, smir);
    k_rr<<<dim3(N_/64,1,2),256,0,stream>>>(W, R1IF_OFF, 0, a_off, lda, aoff, xout_off, xout_ld, 0, D_OFF, inv_s, outp, xmir);
  };

  // ---------- Poisson #1 + K-step ----------
  poisson();
  k_rr<<<dim3(NX/64,1,2),256,0,stream>>>(W, S_OFF, 0, X_OFF, NX, 0, KA_OFF, NXP, 4, -1, 1.0f, nullptr, -1);
  k_ghost2<<<dim3(1,1,2),256,0,stream>>>(W, KA_OFF);
  k_flux<<<dim3(NX/32,1,2),256,0,stream>>>(W, KA_OFF, KA_OFF, NXP, 4, 1,
      MATS_OFF+0*4096, MATS_OFF+1*4096, MATS_OFF+4*4096, MATS_OFF+5*4096,
      E_OFF, FAC_E, FAC_I, 1.0f/DXf, NX, NXP, 1, 0, KB_OFF);
  k_ghost2<<<dim3(1,1,2),256,0,stream>>>(W, KB_OFF);
  k_flux<<<dim3(NX/32,1,2),256,0,stream>>>(W, KB_OFF, KB_OFF, NXP, 4, 1,
      MATS_OFF+0*4096, MATS_OFF+1*4096, MATS_OFF+4*4096, MATS_OFF+5*4096,
      E_OFF, FAC_E, FAC_I, 1.0f/DXf, NX, NXP, 2, KA_OFF, KA_OFF);
  qr(KA_OFF, NXP, 4, NX, SPLIT_QRX, S_OFF, SQRT_DXf, X_OFF, NX, ISQRT_DXf, -1, DOUT_X);

  // GL/GR grams of the (new) X — serve both S-phase and L-phase
  k_gram<<<dim3(SPLIT_X,2,2),256,0,stream>>>(W, 5, X_OFF, NX, -1, 0.f,0.f, PART_OFF, NX, SPLIT_X);
  k_reduce2<<<dim3(2,16,2),256,0,stream>>>(W, PART_OFF, GLR_OFF, SPLIT_X);

  // ---------- Poisson #2 + S-step ----------
  poisson();
  k_gram<<<dim3(SPLIT_X,2,2),256,0,stream>>>(W, 3, X_OFF, NX, E_OFF, 1.0f, 1.0f, PART_OFF, NX, SPLIT_X);
  k_reduce2<<<dim3(2,16,2),256,0,stream>>>(W, PART_OFF, SM_OFF + 2*4096, SPLIT_X);
  k_sstep<<<dim3(2),256,0,stream>>>(W, 1);
  k_sstep<<<dim3(2),256,0,stream>>>(W, 2);

  // ---------- Poisson #3 + L-step ----------
  poisson();
  k_gram<<<dim3(SPLIT_X,2,2),256,0,stream>>>(W, 3, X_OFF, NX, E_OFF, FAC_E, FAC_I, PART_OFF, NX, SPLIT_X);
  k_reduce2<<<dim3(2,16,2),256,0,stream>>>(W, PART_OFF, SM_OFF + 2*4096, SPLIT_X);
  k_rr<<<dim3(NV/64,1,2),256,0,stream>>>(W, S_OFF, 1, V_OFF, NV, 0, LA_OFF, NVP, 4, -1, 1.0f, nullptr, -1);
  k_ghostL<<<dim3(1,1,2),256,0,stream>>>(W);
  auto leval = [&](int Lsrc, int stage, int Ldst, int Lorig) {
    qr(Lsrc, NVP, 4, NV, SPLIT_QRV, SQ_OFF, SQRT_DVf, VQ_OFF, NV, ISQRT_DVf, -1, -1);
    k_gram<<<dim3(SPLIT_VM,2,2),256,0,stream>>>(W, 1, VQ_OFF, NV, -1, 0.f,0.f, PART_OFF, NV, SPLIT_VM);
    k_reduce2<<<dim3(2,16,2),256,0,stream>>>(W, PART_OFF, MATS_OFF + 6*4096, SPLIT_VM);
    k_klr<<<dim3(2),256,0,stream>>>(W, SQ_OFF, 6, 7);
    k_flux<<<dim3(NV/32,1,2),256,0,stream>>>(W, Lsrc, VQ_OFF, NV, 0, 0,
        SM_OFF+2*4096, SM_OFF+3*4096, SM_OFF+0*4096, SM_OFF+1*4096,
        -1, 0.f, 0.f, 1.0f/DVf, NV, NVP, stage, Lorig, Ldst);
  };
  leval(LA_OFF, 1, LB_OFF, 0);
  leval(LB_OFF, 2, LA_OFF, LA_OFF);
  qr(LA_OFF, NVP, 4, NV, SPLIT_QRV, S_OFF, SQRT_DVf, V_OFF, NV, ISQRT_DVf, DOUT_S, DOUT_V);

  (void)in_sizes; (void)n_in; (void)out_size; (void)ws_size;
}

// Round 11
// 1287.786 us; speedup vs baseline: 1.9481x; 1.0994x over previous
//
#include <hip/hip_runtime.h>

#define R 64
#define NX 16384
#define NV 2048
#define NXP (NX+8)
#define NVP (NV+8)
#define TW 64
#define SPLIT_VM 8
#define SPLIT_X 64
#define SPLIT_QRX 128
#define SPLIT_QRV 32

#define DXf 1.220703125e-4f
#define DVf 0.0078125f
#define DTf 0.001f
#define PI_F 3.14159265358979323846f
#define FAC_E (-1.0f)
#define FAC_I (0.01f)
#define ZE_F (-1.0f)
#define ZI_F (1.0f)
#define SQRT_DXf 0.011048543456039806f
#define SQRT_DVf 0.08838834764831845f
#define ISQRT_DXf 90.50966799187808f
#define ISQRT_DVf 11.313708498984761f

// ---------------- workspace layout (float offsets), per-species stride SPS ----
#define X_OFF 0
#define V_OFF 1048576
#define S_OFF 1179648
#define S1_OFF 1183744
#define SQ_OFF 1187840
#define D_OFF 1191936
#define MASS_OFF 1192000
#define MATS_OFF 1196032      /* 8 mats: vplus,vminus,Vm,Vp,Vl,Vr,Vmq,Vpq */
#define SM_OFF 1228800        /* KL,KR,EpM,EmM finals */
#define GLR_OFF 1245184       /* GL, GR (2 x 4096 f32) */
#define R1IF_OFF 1269760      /* f32 Rinv */
#define KA_OFF 1277952        /* 64 x NXP padded */
#define KB_OFF 2327040        /* 64 x NXP padded ; L-phase aliases below */
#define LA_OFF KB_OFF
#define LB_OFF (KB_OFF+131584)
#define VQ_OFF (KB_OFF+394240)
#define PART_OFF 3376128      /* f32 partials; aliased as f64 QR partials */
#define PARTQR_OFF PART_OFF
#define GD_OFF 4686848        /* reduced f64 gram: 4096 doubles */
#define SPS 4695040
// shared region
#define RHO_OFF 9390080
#define E_OFF 9406464
#define FFT1_OFF 9426944
#define FFT2_OFF 9459712
// d_out per-species layout
#define DOUT_SPS 1183744
#define DOUT_X 0
#define DOUT_S 1048576
#define DOUT_V 1052672
// copy-in sizes (float4 units)
#define CP_NX4 262144
#define CP_NR4 1024
#define CP_NV4 32768
#define CP_SP  295936
#define CP_TOT 591872

__device__ __forceinline__ float mm2(float a, float b) {
    return (a*b > 0.0f) ? ((fabsf(a) < fabsf(b)) ? a : b) : 0.0f;
}

// fused input copy: 6 memcpys -> 1 kernel
__global__ __launch_bounds__(256) void k_copyin(float* W, const float* Xe, const float* Se,
    const float* Ve, const float* Xi, const float* Si, const float* Vi)
{
  for (size_t idx = (size_t)blockIdx.x*256 + threadIdx.x; idx < CP_TOT; idx += (size_t)gridDim.x*256) {
    int sp = idx >= CP_SP;
    int e = (int)(idx - (size_t)sp*CP_SP);
    const float* Xs = sp ? Xi : Xe;
    const float* Ss = sp ? Si : Se;
    const float* Vs = sp ? Vi : Ve;
    float* base = W + (size_t)sp*SPS;
    float4 v; float* dst;
    if (e < CP_NX4)               { v = ((const float4*)Xs)[e];            dst = base + X_OFF + 4*(size_t)e; }
    else if (e < CP_NX4+CP_NR4)   { int t = e-CP_NX4; v = ((const float4*)Ss)[t]; dst = base + S_OFF + 4*(size_t)t; }
    else                          { int t = e-CP_NX4-CP_NR4; v = ((const float4*)Vs)[t]; dst = base + V_OFF + 4*(size_t)t; }
    *(float4*)dst = v;
  }
}

// ---------------- generic weighted gram ------
// mode 0: 6 V-matrices   mode 1: Vm/Vp masks from Vq
// mode 3: Ep_mat/Em_mat  mode 5: GL/GR boundary-adjusted X-diff grams
__global__ __launch_bounds__(256) void k_gram(float* W, int mode, int a_off, int lda,
    int e_abs, float fac0, float fac1, int out_off, int N, int nsplit)
{
  int sp = blockIdx.z, mat = blockIdx.y, split = blockIdx.x;
  float* base = W + (size_t)sp*SPS;
  const float* A = base + a_off;
  float fac = sp ? fac1 : fac0;
  float* outp = base + out_off + (size_t)(mat*nsplit + split)*4096;
  int chunk = N / nsplit;
  int xb0 = split * chunk;
  __shared__ float tA[TW][R+1], tB[TW][R+1];
  float acc[4][4] = {};
  int tid = threadIdx.x, ty = tid >> 4, tx = tid & 15;
  for (int xt = 0; xt < chunk; xt += TW) {
    for (int idx = tid; idx < TW*R; idx += 256) {
      int xi = idx & 63, r = idx >> 6;
      int x = xb0 + xt + xi;
      float av, bv;
      if (mode == 0) {
        float vv = A[(size_t)r*lda + x];
        float vs = ((float)x + 0.5f)*DVf - 8.0f;
        if (mat == 0)      { av = vv * (fmaxf(vs,0.f)*DVf); bv = vv; }
        else if (mat == 1) { av = vv * (fminf(vs,0.f)*DVf); bv = vv; }
        else if (mat == 2) { av = vv * ((vs<0.f)?DVf:0.f); bv = vv; }
        else if (mat == 3) { av = vv * ((vs>0.f)?DVf:0.f); bv = vv; }
        else if (mat == 4) { av = vv; bv = (x>=1)   ? (vv - A[(size_t)r*lda + x-1]) : 0.f; }
        else               { av = vv; bv = (x<NV-1) ? (A[(size_t)r*lda + x+1] - vv) : 0.f; }
      } else if (mode == 1) {
        float vv = A[(size_t)r*lda + x];
        float vs = ((float)x + 0.5f)*DVf - 8.0f;
        float w = (mat==0) ? ((vs<0.f)?DVf:0.f) : ((vs>0.f)?DVf:0.f);
        av = vv*w; bv = vv;
      } else if (mode == 3) {
        float e = W[e_abs + x] * fac;
        float vv = A[(size_t)r*lda + x];
        av = vv * (((mat==0) ? fmaxf(e,0.f) : fminf(e,0.f)) * DXf);
        bv = vv;
      } else { // mode 5: GL (mat0), GR (mat1)
        float vv = A[(size_t)r*lda + x];
        av = vv;
        if (mat == 0) bv = (x>=1)  ? (vv - A[(size_t)r*lda + x-1]) : vv;
        else          bv = (x<N-1) ? (A[(size_t)r*lda + x+1] - vv) : -vv;
      }
      tA[xi][r] = av; tB[xi][r] = bv;
    }
    __syncthreads();
    for (int xi = 0; xi < TW; ++xi) {
      float a0 = tA[xi][ty*4+0], a1 = tA[xi][ty*4+1], a2 = tA[xi][ty*4+2], a3 = tA[xi][ty*4+3];
      float b0 = tB[xi][tx*4+0], b1 = tB[xi][tx*4+1], b2 = tB[xi][tx*4+2], b3 = tB[xi][tx*4+3];
      acc[0][0]+=a0*b0; acc[0][1]+=a0*b1; acc[0][2]+=a0*b2; acc[0][3]+=a0*b3;
      acc[1][0]+=a1*b0; acc[1][1]+=a1*b1; acc[1][2]+=a1*b2; acc[1][3]+=a1*b3;
      acc[2][0]+=a2*b0; acc[2][1]+=a2*b1; acc[2][2]+=a2*b2; acc[2][3]+=a2*b3;
      acc[3][0]+=a3*b0; acc[3][1]+=a3*b1; acc[3][2]+=a3*b2; acc[3][3]+=a3*b3;
    }
    __syncthreads();
  }
  #pragma unroll
  for (int i = 0; i < 4; ++i)
    #pragma unroll
    for (int j = 0; j < 4; ++j)
      outp[(ty*4+i)*64 + tx*4 + j] = acc[i][j];
}

// gram with fp64 accumulation for QR (A only)
__global__ __launch_bounds__(256) void k_gram_qr(float* W, int a_off, int lda, int aoff,
    int N, int nsplit, int outd_off)
{
  int sp = blockIdx.z, split = blockIdx.x;
  float* base = W + (size_t)sp*SPS;
  const float* A = base + a_off + aoff;
  double* outp = (double*)(base + outd_off) + (size_t)split*4096;
  int chunk = N / nsplit, x0 = split*chunk;
  __shared__ float tA[TW][R+1];
  double acc[4][4] = {};
  int tid = threadIdx.x, ty = tid >> 4, tx = tid & 15;
  for (int xt = 0; xt < chunk; xt += TW) {
    for (int idx = tid; idx < TW*R; idx += 256) {
      int xi = idx & 63, r = idx >> 6;
      tA[xi][r] = A[(size_t)r*lda + x0 + xt + xi];
    }
    __syncthreads();
    for (int xi = 0; xi < TW; ++xi) {
      double a0 = tA[xi][ty*4+0], a1 = tA[xi][ty*4+1], a2 = tA[xi][ty*4+2], a3 = tA[xi][ty*4+3];
      double b0 = tA[xi][tx*4+0], b1 = tA[xi][tx*4+1], b2 = tA[xi][tx*4+2], b3 = tA[xi][tx*4+3];
      acc[0][0]+=a0*b0; acc[0][1]+=a0*b1; acc[0][2]+=a0*b2; acc[0][3]+=a0*b3;
      acc[1][0]+=a1*b0; acc[1][1]+=a1*b1; acc[1][2]+=a1*b2; acc[1][3]+=a1*b3;
      acc[2][0]+=a2*b0; acc[2][1]+=a2*b1; acc[2][2]+=a2*b2; acc[2][3]+=a2*b3;
      acc[3][0]+=a3*b0; acc[3][1]+=a3*b1; acc[3][2]+=a3*b2; acc[3][3]+=a3*b3;
    }
    __syncthreads();
  }
  #pragma unroll
  for (int i = 0; i < 4; ++i)
    #pragma unroll
    for (int j = 0; j < 4; ++j)
      outp[(ty*4+i)*64 + tx*4 + j] = acc[i][j];
}

__global__ __launch_bounds__(256) void k_reduce2(float* W, int src_off, int dst_off, int nsplit)
{
  int sp = blockIdx.z, mat = blockIdx.x;
  int e = blockIdx.y*256 + threadIdx.x;
  float* base = W + (size_t)sp*SPS;
  const float* src = base + src_off + (size_t)mat*nsplit*4096 + e;
  float s = 0;
  for (int k = 0; k < nsplit; ++k) s += src[(size_t)k*4096];
  base[dst_off + (size_t)mat*4096 + e] = s;
}

__global__ __launch_bounds__(256) void k_reduced(float* W, int src_off, int dst_off, int nsplit)
{
  int sp = blockIdx.z;
  int e = blockIdx.x*256 + threadIdx.x;
  float* base = W + (size_t)sp*SPS;
  const double* src = (const double*)(base + src_off) + e;
  double s = 0;
  for (int k = 0; k < nsplit; ++k) s += src[(size_t)k*4096];
  ((double*)(base + dst_off))[e] = s;
}

// C[j][x] = alpha*d[j]* sum_r A[r][j]*B[r][x]
__global__ __launch_bounds__(256) void k_rr(float* W, int a_off, int transA, int b_off,
    int ldb, int boff, int c_off, int ldc, int coff, int d_off, float alpha,
    float* dout, int dmir_off)
{
  int sp = blockIdx.z;
  float* base = W + (size_t)sp*SPS;
  const float* A = base + a_off;
  const float* B = base + b_off + boff;
  float* C = base + c_off + coff;
  float* M = (dmir_off >= 0) ? (dout + (size_t)sp*DOUT_SPS + dmir_off) : nullptr;
  __shared__ float tA[R][R+1];
  __shared__ float dsc[R];
  int tid = threadIdx.x;
  for (int idx = tid; idx < R*R; idx += 256) {
    int r = idx >> 6, j = idx & 63;
    tA[r][j] = transA ? A[j*R + r] : A[idx];
  }
  if (tid < R) dsc[tid] = (d_off >= 0) ? base[d_off + tid] : 1.0f;
  __syncthreads();
  int ty = tid >> 4, tx = tid & 15;
  int x0 = blockIdx.x*64 + tx*4;
  float acc[4][4] = {};
  for (int r = 0; r < R; ++r) {
    float4 bv = *(const float4*)(B + (size_t)r*ldb + x0);
    float a0 = tA[r][ty*4+0], a1 = tA[r][ty*4+1], a2 = tA[r][ty*4+2], a3 = tA[r][ty*4+3];
    acc[0][0]+=a0*bv.x; acc[0][1]+=a0*bv.y; acc[0][2]+=a0*bv.z; acc[0][3]+=a0*bv.w;
    acc[1][0]+=a1*bv.x; acc[1][1]+=a1*bv.y; acc[1][2]+=a1*bv.z; acc[1][3]+=a1*bv.w;
    acc[2][0]+=a2*bv.x; acc[2][1]+=a2*bv.y; acc[2][2]+=a2*bv.z; acc[2][3]+=a2*bv.w;
    acc[3][0]+=a3*bv.x; acc[3][1]+=a3*bv.y; acc[3][2]+=a3*bv.z; acc[3][3]+=a3*bv.w;
  }
  #pragma unroll
  for (int i = 0; i < 4; ++i) {
    int j = ty*4 + i;
    float s = alpha * dsc[j];
    float4 o = make_float4(acc[i][0]*s, acc[i][1]*s, acc[i][2]*s, acc[i][3]*s);
    *(float4*)(C + (size_t)j*ldc + x0) = o;
    if (M) *(float4*)(M + (size_t)j*ldc + x0) = o;
  }
}

// fused slope-limited flux divergence + extra term + SSPRK2 combine.
// gmode 1: boundary blocks compute projection ghosts in-LDS (Vm=mats2, Vp=mats3)
// gmode 0: boundary blocks zero the ghost columns
__global__ __launch_bounds__(256) void k_flux(float* W, int U_off, int Kx_off, int ldkx,
    int kxoff, int useWin, int P_off, int Mi_off, int A2_off, int B2_off,
    int e_abs, float fac0, float fac1, float dh_inv, int N, int ldp,
    int stage, int orig_off, int out_off, int gmode)
{
  int sp = blockIdx.z;
  float* base = W + (size_t)sp*SPS;
  const float* U  = base + U_off;
  const float* Kx = base + Kx_off;
  const float* Pm = base + P_off;
  const float* Mm = base + Mi_off;
  const float* Am = base + A2_off;
  const float* Bm = base + B2_off;
  float fac = sp ? fac1 : fac0;
  int x0 = blockIdx.x * 32;
  __shared__ float win[R][37];
  __shared__ float dLt[32][R+1];
  __shared__ float dRt[32][R+1];
  __shared__ float KTt[32][R+1];
  int tid = threadIdx.x;
  for (int idx = tid; idx < R*36; idx += 256) {
    int c = idx % 36, m = idx / 36;
    win[m][c] = U[(size_t)m*ldp + x0 + 2 + c];
  }
  __syncthreads();
  bool left = (blockIdx.x == 0), right = (blockIdx.x == (unsigned)(N/32 - 1));
  if (left || right) {
    if (gmode == 1) {
      if (tid < 128) {
        int jj = tid & 63, c = tid >> 6;
        if (left) {
          const float* Mv = base + MATS_OFF + 2*4096;
          int srcl = (c==0) ? 3 : 2;        // dst local 0<-padded5, 1<-padded4
          float s = 0;
          for (int m = 0; m < R; ++m) s += Mv[jj*R + m] * win[m][srcl];
          win[jj][c] = s;                   // write cols 0,1 (disjoint from read cols 2,3)
        } else {
          const float* Mv = base + MATS_OFF + 3*4096;
          int srcl = (c==0) ? 33 : 32;      // dst local 34<-33, 35<-32
          float s = 0;
          for (int m = 0; m < R; ++m) s += Mv[jj*R + m] * win[m][srcl];
          win[jj][34 + c] = s;
        }
      }
    } else {
      if (tid < 128) {
        int jj = tid & 63, c = tid >> 6;
        if (left) win[jj][c] = 0.f;
        else      win[jj][34 + c] = 0.f;
      }
    }
    __syncthreads();
  }
  for (int idx = tid; idx < R*32; idx += 256) {
    int xi = idx & 31, m = idx >> 5;
    float u0 = win[m][xi], u1 = win[m][xi+1], u2 = win[m][xi+2], u3 = win[m][xi+3], u4 = win[m][xi+4];
    float d01 = u1-u0, d12 = u2-u1, d23 = u3-u2, d34 = u4-u3;
    float s1 = mm2(d01,d12), s2 = mm2(d12,d23), s3 = mm2(d23,d34);
    dLt[xi][m] = ((u2 + 0.5f*s2) - (u1 + 0.5f*s1)) * dh_inv;
    dRt[xi][m] = ((u3 - 0.5f*s3) - (u2 - 0.5f*s2)) * dh_inv;
    KTt[xi][m] = useWin ? u2 : Kx[(size_t)m*ldkx + kxoff + x0 + xi];
  }
  __syncthreads();
  int ty = tid >> 4, tx = tid & 15;
  int j0 = ty*4;
  float aP[4][2] = {}, aM[4][2] = {}, aA[4][2] = {}, aB[4][2] = {};
  for (int m = 0; m < R; ++m) {
    float dl0 = dLt[tx*2][m],   dl1 = dLt[tx*2+1][m];
    float dr0 = dRt[tx*2][m],   dr1 = dRt[tx*2+1][m];
    float kt0 = KTt[tx*2][m],   kt1 = KTt[tx*2+1][m];
    #pragma unroll
    for (int i = 0; i < 4; ++i) {
      float p = Pm[(j0+i)*R + m], q = Mm[(j0+i)*R + m];
      float a = Am[(j0+i)*R + m], b = Bm[(j0+i)*R + m];
      aP[i][0] += p*dl0; aP[i][1] += p*dl1;
      aM[i][0] += q*dr0; aM[i][1] += q*dr1;
      aA[i][0] += a*kt0; aA[i][1] += a*kt1;
      aB[i][0] += b*kt0; aB[i][1] += b*kt1;
    }
  }
  const float* orig = base + orig_off;
  float* out = base + out_off;
  for (int xx = 0; xx < 2; ++xx) {
    int x = x0 + tx*2 + xx;
    float w1, w2;
    if (e_abs >= 0) { float e = W[e_abs + x]; w1 = fac*fmaxf(e,0.f); w2 = fac*fminf(e,0.f); }
    else { float vs = ((float)x + 0.5f)*DVf - 8.0f; w1 = fmaxf(vs,0.f); w2 = fminf(vs,0.f); }
    #pragma unroll
    for (int i = 0; i < 4; ++i) {
      int j = j0 + i;
      float rhs = -(aP[i][xx] + aM[i][xx] + w1*aA[i][xx] + w2*aB[i][xx]);
      float uval = win[j][tx*2 + xx + 2];
      float res;
      if (stage == 1) res = uval + DTf*rhs;
      else res = 0.5f*(orig[(size_t)j*ldp + 4 + x] + uval + DTf*rhs);
      out[(size_t)j*ldp + 4 + x] = res;
    }
  }
}

// CholeskyQR1 tail, 512 threads. GE (1 barrier/step) + normalize -> R;
// 3-level recursive-blocked tri-inverse -> Rinv (8x8 lane-local, then 2-phase merges);
// want_sign: T = A_top@Rinv + LAPACK sign chain -> D; S_out = [D*]R*sscale (+ mirror).
// NOTE: reference's L_rhs contracts X-rank with QR-rank indices directly, so the
// LAPACK sign convention does NOT cancel — ALL QRs must emulate signs.
__global__ __launch_bounds__(512) void k_cholA(float* W, int gd_off,
    int a_off, int lda, int aoff, int sout_off, float sscale,
    float* dout, int dmir_off, int want_sign)
{
  int sp = blockIdx.z;
  float* base = W + (size_t)sp*SPS;
  const double* GD = (const double*)(base + gd_off);
  const float* A = base + a_off + aoff;
  float* Rinv = base + R1IF_OFF;
  __shared__ double G[R][R+1];
  __shared__ double Wi[R][R+1];
  __shared__ double T[R][R+1];
  __shared__ float  As[R][R+1];
  __shared__ double Pb[32][33];
  __shared__ double dinv[R];
  __shared__ double dsh[R];
  int tid = threadIdx.x;
  int j = tid & 63, q = tid >> 6;
  for (int e = tid; e < 4096; e += 512) {
    G[e>>6][e&63] = GD[e];
    if (want_sign) As[e>>6][e&63] = A[(size_t)(e>>6)*lda + (e&63)];
  }
  __syncthreads();
  // ---- Gaussian elimination, one barrier per step ----
  for (int k = 0; k < R; ++k) {
    if (j > k) {
      double gkj = G[k][j] / G[k][k];
      for (int i = k+1+q; i <= j; i += 8) G[i][j] -= G[k][i]*gkj;
    }
    __syncthreads();
  }
  if (tid < R) dinv[tid] = 1.0 / sqrt(G[tid][tid]);
  __syncthreads();
  for (int i = q; i <= j; i += 8) G[i][j] *= dinv[i];
  __syncthreads();
  if (tid < R) dinv[tid] = 1.0 / G[tid][tid];
  __syncthreads();
  // ---- level 0: 8x8 diagonal blocks, lane-local per column ----
  if (q == 0) {
    Wi[j][j] = dinv[j];
    int blo = j & ~7;
    for (int i = j-1; i >= blo; --i) {
      double s = 0;
      for (int m = i+1; m <= j; ++m) s += G[i][m]*Wi[m][j];
      Wi[i][j] = -s * dinv[i];
    }
  }
  __syncthreads();
  // ---- merge levels n = 8,16,32: W12 = -W11 * (R12 * W22) ----
  for (int lg = 3; lg <= 5; ++lg) {
    int n = 1 << lg;
    int total = 32 << lg;   // (32>>lg) pairs * n*n
    for (int e = tid; e < total; e += 512) {
      int p = e >> (2*lg); int i = (e >> lg) & (n-1); int jj = e & (n-1);
      int i0 = 2*n*p, j0 = i0 + n;
      double s = 0;
      for (int k2 = 0; k2 <= jj; ++k2) s += G[i0+i][j0+k2]*Wi[j0+k2][j0+jj];
      Pb[p*n + i][jj] = s;
    }
    __syncthreads();
    for (int e = tid; e < total; e += 512) {
      int p = e >> (2*lg); int i = (e >> lg) & (n-1); int jj = e & (n-1);
      int i0 = 2*n*p, j0 = i0 + n;
      double s = 0;
      for (int k2 = i; k2 < n; ++k2) s += Wi[i0+i][i0+k2]*Pb[p*n + k2][jj];
      Wi[i0+i][j0+jj] = -s;
    }
    __syncthreads();
  }
  // Rinv f32 out
  for (int e = tid; e < 4096; e += 512) {
    int i = e>>6, jj = e&63;
    Rinv[e] = (i<=jj) ? (float)Wi[i][jj] : 0.0f;
  }
  float* mir = (dmir_off >= 0) ? (dout + (size_t)sp*DOUT_SPS + dmir_off) : nullptr;
  if (want_sign) {
    // T[x][j] = sum_m Wi[m][j] * As[m][x]
    for (int x = q; x < R; x += 8) {
      double s = 0;
      for (int m = 0; m <= j; ++m) s += Wi[m][j]*(double)As[m][x];
      T[x][j] = s;
    }
    __syncthreads();
    // ---- LAPACK Householder sign chain ----
    for (int k = 0; k < R; ++k) {
      double tkk = T[k][k];
      double d = (tkk >= 0.0) ? -1.0 : 1.0;
      if (tid == k) dsh[k] = d;
      if (j > k) {
        double c = d * T[k][j] / (1.0 + fabs(tkk));
        for (int m = k+1+q; m < R; m += 8) T[m][j] += c * T[m][k];
      }
      __syncthreads();
    }
    if (tid < 64) base[D_OFF + tid] = (float)dsh[tid];
    for (int e = tid; e < 4096; e += 512) {
      int i = e >> 6, jj = e & 63;
      float v = (i <= jj) ? (float)(dsh[i] * G[i][jj] * (double)sscale) : 0.0f;
      base[sout_off + e] = v;
      if (mir) mir[e] = v;
    }
  } else {
    for (int e = tid; e < 4096; e += 512) {
      int i = e >> 6, jj = e & 63;
      float v = (i <= jj) ? (float)(G[i][jj] * (double)sscale) : 0.0f;
      base[sout_off + e] = v;
      if (mir) mir[e] = v;
    }
  }
}

// KL/KR from R x R algebra: KL = GL@S - x0⊗(Vm(S^T x0)), KR = GR@S + x1⊗(Vp(S^T x1))
__global__ __launch_bounds__(256) void k_klr(float* W, int s_off, int vm_idx, int vp_idx)
{
  int sp = blockIdx.x;
  float* base = W + (size_t)sp*SPS;
  __shared__ float Cb[4096];
  __shared__ float x0s[R], x1s[R], u0[R], u1[R], g0[R], g1[R];
  int tid = threadIdx.x, ty = tid>>4, tx = tid&15;
  const float* Sin = base + s_off;
  for (int e = tid; e < 4096; e += 256) Cb[e] = Sin[e];
  if (tid < R) { x0s[tid] = base[X_OFF + (size_t)tid*NX]; x1s[tid] = base[X_OFF + (size_t)tid*NX + NX-1]; }
  __syncthreads();
  if (tid < R) {
    float s0=0,s1=0;
    for (int m=0;m<R;++m){ float c=Cb[m*64+tid]; s0+=c*x0s[m]; s1+=c*x1s[m]; }
    u0[tid]=s0; u1[tid]=s1;
  }
  __syncthreads();
  if (tid < R) {
    const float* Vm = base + MATS_OFF + vm_idx*4096;
    const float* Vp = base + MATS_OFF + vp_idx*4096;
    float s0=0,s1=0;
    for (int c=0;c<R;++c){ s0+=Vm[tid*64+c]*u0[c]; s1+=Vp[tid*64+c]*u1[c]; }
    g0[tid]=s0; g1[tid]=s1;
  }
  __syncthreads();
  const float* GLg = base + GLR_OFF;
  const float* GRg = base + GLR_OFF + 4096;
  float aKL[4][4]={}, aKR[4][4]={};
  for (int m=0;m<R;++m) {
    float gl[4], gr[4], cj[4];
    #pragma unroll
    for (int i=0;i<4;++i){ gl[i]=GLg[(ty*4+i)*64+m]; gr[i]=GRg[(ty*4+i)*64+m]; }
    #pragma unroll
    for (int j=0;j<4;++j) cj[j]=Cb[m*64+tx*4+j];
    #pragma unroll
    for (int i=0;i<4;++i)
      #pragma unroll
      for (int j=0;j<4;++j){ aKL[i][j]+=gl[i]*cj[j]; aKR[i][j]+=gr[i]*cj[j]; }
  }
  #pragma unroll
  for (int i=0;i<4;++i)
    #pragma unroll
    for (int j=0;j<4;++j){
      int e=(ty*4+i)*64+tx*4+j;
      base[SM_OFF+e]      = aKL[i][j] - x0s[ty*4+i]*g0[tx*4+j];
      base[SM_OFF+4096+e] = aKR[i][j] + x1s[ty*4+i]*g1[tx*4+j];
    }
}

// S-step: fused KL/KR (R x R algebra) + rhs + SSPRK2 combine.
__global__ __launch_bounds__(256) void k_sstep(float* W, int stage)
{
  int sp = blockIdx.x;
  float* base = W + (size_t)sp*SPS;
  float fac = sp ? FAC_I : FAC_E;
  __shared__ float Ab[4096], Bb[4096], Cb[4096];
  __shared__ float x0s[R], x1s[R], u0[R], u1[R], g0[R], g1[R];
  int tid = threadIdx.x, ty = tid >> 4, tx = tid & 15;
  const float* Sin = base + ((stage==1)? S_OFF : S1_OFF);
  for (int e = tid; e < 4096; e += 256) Cb[e] = Sin[e];
  if (tid < R) { x0s[tid] = base[X_OFF + (size_t)tid*NX]; x1s[tid] = base[X_OFF + (size_t)tid*NX + NX-1]; }
  __syncthreads();
  if (tid < R) {
    float s0=0,s1=0;
    for (int m=0;m<R;++m){ float c=Cb[m*64+tid]; s0+=c*x0s[m]; s1+=c*x1s[m]; }
    u0[tid]=s0; u1[tid]=s1;
  }
  __syncthreads();
  if (tid < R) {
    const float* Vm = base + MATS_OFF + 2*4096;
    const float* Vp = base + MATS_OFF + 3*4096;
    float s0=0,s1=0;
    for (int c=0;c<R;++c){ s0+=Vm[tid*64+c]*u0[c]; s1+=Vp[tid*64+c]*u1[c]; }
    g0[tid]=s0; g1[tid]=s1;
  }
  __syncthreads();
  {
    const float* GLg = base + GLR_OFF;
    const float* GRg = base + GLR_OFF + 4096;
    float aKL[4][4]={}, aKR[4][4]={};
    for (int m=0;m<R;++m) {
      float gl[4], gr[4], cj[4];
      #pragma unroll
      for (int i=0;i<4;++i){ gl[i]=GLg[(ty*4+i)*64+m]; gr[i]=GRg[(ty*4+i)*64+m]; }
      #pragma unroll
      for (int j=0;j<4;++j) cj[j]=Cb[m*64+tx*4+j];
      #pragma unroll
      for (int i=0;i<4;++i)
        #pragma unroll
        for (int j=0;j<4;++j){ aKL[i][j]+=gl[i]*cj[j]; aKR[i][j]+=gr[i]*cj[j]; }
    }
    #pragma unroll
    for (int i=0;i<4;++i)
      #pragma unroll
      for (int j=0;j<4;++j){
        int e=(ty*4+i)*64+tx*4+j;
        Ab[e] = aKL[i][j] - x0s[ty*4+i]*g0[tx*4+j];
        Bb[e] = aKR[i][j] + x1s[ty*4+i]*g1[tx*4+j];
      }
  }
  __syncthreads();
  const float* vpm = base + MATS_OFF + 0*4096;
  const float* vmm = base + MATS_OFF + 1*4096;
  const float* vlm = base + MATS_OFF + 4*4096;
  const float* vrm = base + MATS_OFF + 5*4096;
  float accV[4][4] = {}, accE[4][4] = {};
  for (int m = 0; m < R; ++m) {
    float kl[4], kr[4], vpj[4], vmj[4];
    #pragma unroll
    for (int i = 0; i < 4; ++i) { kl[i] = Ab[(ty*4+i)*64+m]; kr[i] = Bb[(ty*4+i)*64+m]; }
    #pragma unroll
    for (int j = 0; j < 4; ++j) { vpj[j] = vpm[(tx*4+j)*64+m]; vmj[j] = vmm[(tx*4+j)*64+m]; }
    #pragma unroll
    for (int i = 0; i < 4; ++i)
      #pragma unroll
      for (int j = 0; j < 4; ++j)
        accV[i][j] += kl[i]*vpj[j] + kr[i]*vmj[j];
  }
  __syncthreads();
  for (int e = tid; e < 4096; e += 256) Ab[e] = base[SM_OFF + 2*4096 + e];   // EpM
  __syncthreads();
  float t1[4][4] = {};
  for (int m = 0; m < R; ++m) {
    float ar[4], cj[4];
    #pragma unroll
    for (int i = 0; i < 4; ++i) ar[i] = Ab[(ty*4+i)*64+m];
    #pragma unroll
    for (int j = 0; j < 4; ++j) cj[j] = Cb[m*64 + tx*4+j];
    #pragma unroll
    for (int i = 0; i < 4; ++i)
      #pragma unroll
      for (int j = 0; j < 4; ++j) t1[i][j] += ar[i]*cj[j];
  }
  __syncthreads();
  #pragma unroll
  for (int i = 0; i < 4; ++i)
    #pragma unroll
    for (int j = 0; j < 4; ++j) Bb[(ty*4+i)*64 + tx*4+j] = t1[i][j];
  __syncthreads();
  for (int m = 0; m < R; ++m) {
    float ar[4], vj[4];
    #pragma unroll
    for (int i = 0; i < 4; ++i) ar[i] = Bb[(ty*4+i)*64+m];
    #pragma unroll
    for (int j = 0; j < 4; ++j) vj[j] = vlm[(tx*4+j)*64+m];
    #pragma unroll
    for (int i = 0; i < 4; ++i)
      #pragma unroll
      for (int j = 0; j < 4; ++j) accE[i][j] += ar[i]*vj[j];
  }
  __syncthreads();
  for (int e = tid; e < 4096; e += 256) Ab[e] = base[SM_OFF + 3*4096 + e];  // EmM
  __syncthreads();
  float t2[4][4] = {};
  for (int m = 0; m < R; ++m) {
    float ar[4], cj[4];
    #pragma unroll
    for (int i = 0; i < 4; ++i) ar[i] = Ab[(ty*4+i)*64+m];
    #pragma unroll
    for (int j = 0; j < 4; ++j) cj[j] = Cb[m*64 + tx*4+j];
    #pragma unroll
    for (int i = 0; i < 4; ++i)
      #pragma unroll
      for (int j = 0; j < 4; ++j) t2[i][j] += ar[i]*cj[j];
  }
  __syncthreads();
  #pragma unroll
  for (int i = 0; i < 4; ++i)
    #pragma unroll
    for (int j = 0; j < 4; ++j) Bb[(ty*4+i)*64 + tx*4+j] = t2[i][j];
  __syncthreads();
  for (int m = 0; m < R; ++m) {
    float ar[4], vj[4];
    #pragma unroll
    for (int i = 0; i < 4; ++i) ar[i] = Bb[(ty*4+i)*64+m];
    #pragma unroll
    for (int j = 0; j < 4; ++j) vj[j] = vrm[(tx*4+j)*64+m];
    #pragma unroll
    for (int i = 0; i < 4; ++i)
      #pragma unroll
      for (int j = 0; j < 4; ++j) accE[i][j] += ar[i]*vj[j];
  }
  #pragma unroll
  for (int i = 0; i < 4; ++i)
    #pragma unroll
    for (int j = 0; j < 4; ++j) {
      int e = (ty*4+i)*64 + tx*4+j;
      float rhs = accV[i][j] + fac*accE[i][j];
      if (stage == 1) base[S1_OFF + e] = base[S_OFF + e] + DTf*rhs;
      else base[S_OFF + e] = 0.5f*(base[S_OFF + e] + base[S1_OFF + e] + DTf*rhs);
    }
}

// mass[r] = (V @ 1) * DV  — V constant until the final QR, compute once
__global__ __launch_bounds__(256) void k_mass(float* W)
{
  int sp = blockIdx.x;
  float* base = W + (size_t)sp*SPS;
  const float* V = base + V_OFF;
  __shared__ float red[R][4];
  int tid = threadIdx.x;
  int r = tid >> 2, q = tid & 3;
  float s = 0;
  for (int v = q; v < NV; v += 4) s += V[(size_t)r*NV + v];
  red[r][q] = s;
  __syncthreads();
  if (tid < R) base[MASS_OFF + tid] = (red[tid][0]+red[tid][1]+red[tid][2]+red[tid][3]) * DVf;
}

// rho with inline per-species charge vector c = Z * S @ mass
__global__ __launch_bounds__(256) void k_rho(float* W)
{
  __shared__ float cs[2][R];
  int tid = threadIdx.x;
  if (tid < 128) {
    int sp = tid >> 6, r = tid & 63;
    const float* S = W + (size_t)sp*SPS + S_OFF;
    const float* ms = W + (size_t)sp*SPS + MASS_OFF;
    float c = 0;
    for (int jj = 0; jj < R; ++jj) c += S[r*R + jj] * ms[jj];
    cs[sp][r] = c * (sp ? ZI_F : ZE_F);
  }
  __syncthreads();
  int x = blockIdx.x*256 + tid;
  float s = 0;
  for (int r = 0; r < R; ++r) s += W[X_OFF + (size_t)r*NX + x] * cs[0][r];
  for (int r = 0; r < R; ++r) s += W[(size_t)SPS + X_OFF + (size_t)r*NX + x] * cs[1][r];
  W[RHO_OFF + x] = s;
}

// -------- FFT: length-128 radix-2 DIT in LDS, 64 threads --------
__device__ inline void fft128fwd(float2* b, int t)
{
  __syncthreads();
  int r0 = (int)(__brev((unsigned)t) >> 25);
  int r1 = (int)(__brev((unsigned)(t+64)) >> 25);
  float2 a0 = b[r0], a1 = b[r1];
  __syncthreads();
  b[t] = a0; b[t+64] = a1;
  for (int s = 1; s <= 7; ++s) {
    __syncthreads();
    int half = 1 << (s-1);
    int jj = t & (half-1);
    int g  = t >> (s-1);
    int pos = (g << s) + jj;
    float ang = -2.0f*PI_F*(float)jj / (float)(1 << s);
    float sn, cs; sincosf(ang, &sn, &cs);
    float2 u = b[pos], wv = b[pos+half];
    float2 v = make_float2(wv.x*cs - wv.y*sn, wv.x*sn + wv.y*cs);
    b[pos] = make_float2(u.x+v.x, u.y+v.y);
    b[pos+half] = make_float2(u.x-v.x, u.y-v.y);
  }
}

__global__ __launch_bounds__(64) void k_fftA(float* W, int rin_off, int cin_off, int out_off)
{
  __shared__ float2 bb[128];
  int n1 = blockIdx.x, t = threadIdx.x;
  if (rin_off >= 0) {
    const float* rin = W + rin_off;
    bb[t]    = make_float2(rin[n1 + 128*t], 0.f);
    bb[t+64] = make_float2(rin[n1 + 128*(t+64)], 0.f);
  } else {
    const float2* cin = (const float2*)(W + cin_off);
    bb[t] = cin[n1 + 128*t]; bb[t+64] = cin[n1 + 128*(t+64)];
  }
  fft128fwd(bb, t);
  __syncthreads();
  float2* outp = (float2*)(W + out_off);
  for (int kk = 0; kk < 2; ++kk) {
    int k2 = t + 64*kk;
    float ang = -2.0f*PI_F*(float)(n1*k2) * (1.0f/16384.0f);
    float sn, cs; sincosf(ang, &sn, &cs);
    float2 v = bb[k2];
    outp[k2*128 + n1] = make_float2(v.x*cs - v.y*sn, v.x*sn + v.y*cs);
  }
}

__global__ __launch_bounds__(64) void k_fftB(float* W, int in_off, int out_off)
{
  __shared__ float2 bb[128];
  int k2 = blockIdx.x, t = threadIdx.x;
  const float2* in = (const float2*)(W + in_off);
  bb[t] = in[k2*128 + t]; bb[t+64] = in[k2*128 + t + 64];
  fft128fwd(bb, t);
  __syncthreads();
  float2* outp = (float2*)(W + out_off);
  for (int kk = 0; kk < 2; ++kk) {
    int k1 = t + 64*kk;
    int j = k2 + 128*k1;
    float2 X = bb[k1];
    float2 Hc;
    if (j == 0) Hc = make_float2(0.f, 0.f);
    else {
      float kphys = PI_F * (float)((j < 8192) ? j : (j - 16384));
      Hc = make_float2(X.y / kphys, X.x / kphys);
    }
    outp[j] = Hc;
  }
}

__global__ __launch_bounds__(64) void k_fftD(float* W, int in_off, int e_off)
{
  __shared__ float2 bb[128];
  int k2 = blockIdx.x, t = threadIdx.x;
  const float2* in = (const float2*)(W + in_off);
  bb[t] = in[k2*128 + t]; bb[t+64] = in[k2*128 + t + 64];
  fft128fwd(bb, t);
  __syncthreads();
  for (int kk = 0; kk < 2; ++kk) {
    int k1 = t + 64*kk;
    W[e_off + k2 + 128*k1] = bb[k1].x * (1.0f/16384.0f);
  }
}

// ----------------------------------------------------------------------------
extern "C" void kernel_launch(void* const* d_in, const int* in_sizes, int n_in,
                              void* d_out, int out_size, void* d_ws, size_t ws_size,
                              hipStream_t stream)
{
  float* W = (float*)d_ws;
  float* outp = (float*)d_out;
  k_copyin<<<1024,256,0,stream>>>(W, (const float*)d_in[0], (const float*)d_in[1],
      (const float*)d_in[2], (const float*)d_in[3], (const float*)d_in[4], (const float*)d_in[5]);

  // V-derived matrices (vplus,vminus,Vm,Vp,Vl,Vr) + mass
  k_gram<<<dim3(SPLIT_VM,6,2),256,0,stream>>>(W, 0, V_OFF, NV, -1, 0.f,0.f, PART_OFF, NV, SPLIT_VM);
  k_reduce2<<<dim3(6,16,2),256,0,stream>>>(W, PART_OFF, MATS_OFF, SPLIT_VM);
  k_mass<<<dim3(2),256,0,stream>>>(W);

  auto poisson = [&]() {
    k_rho<<<dim3(NX/256),256,0,stream>>>(W);
    k_fftA<<<dim3(128),64,0,stream>>>(W, RHO_OFF, -1, FFT1_OFF);
    k_fftB<<<dim3(128),64,0,stream>>>(W, FFT1_OFF, FFT2_OFF);
    k_fftA<<<dim3(128),64,0,stream>>>(W, -1, FFT2_OFF, FFT1_OFF);
    k_fftD<<<dim3(128),64,0,stream>>>(W, FFT1_OFF, E_OFF);
  };

  // CholeskyQR1 + LAPACK-sign emulation (signs REQUIRED for all QRs; see k_cholA note)
  auto qr = [&](int a_off, int lda, int aoff, int N_, int nsplit,
                int sout_off, float sscale, int xout_off, int xout_ld, float inv_s,
                int smir, int xmir) {
    k_gram_qr<<<dim3(nsplit,1,2),256,0,stream>>>(W, a_off, lda, aoff, N_, nsplit, PARTQR_OFF);
    k_reduced<<<dim3(16,1,2),256,0,stream>>>(W, PARTQR_OFF, GD_OFF, nsplit);
    k_cholA<<<dim3(1,1,2),512,0,stream>>>(W, GD_OFF, a_off, lda, aoff, sout_off, sscale, outp, smir, 1);
    k_rr<<<dim3(N_/64,1,2),256,0,stream>>>(W, R1IF_OFF, 0, a_off, lda, aoff, xout_off, xout_ld, 0,
                                           D_OFF, inv_s, outp, xmir);
  };

  // ---------- Poisson #1 + K-step ----------
  poisson();
  k_rr<<<dim3(NX/64,1,2),256,0,stream>>>(W, S_OFF, 0, X_OFF, NX, 0, KA_OFF, NXP, 4, -1, 1.0f, nullptr, -1);
  k_flux<<<dim3(NX/32,1,2),256,0,stream>>>(W, KA_OFF, KA_OFF, NXP, 4, 1,
      MATS_OFF+0*4096, MATS_OFF+1*4096, MATS_OFF+4*4096, MATS_OFF+5*4096,
      E_OFF, FAC_E, FAC_I, 1.0f/DXf, NX, NXP, 1, 0, KB_OFF, 1);
  k_flux<<<dim3(NX/32,1,2),256,0,stream>>>(W, KB_OFF, KB_OFF, NXP, 4, 1,
      MATS_OFF+0*4096, MATS_OFF+1*4096, MATS_OFF+4*4096, MATS_OFF+5*4096,
      E_OFF, FAC_E, FAC_I, 1.0f/DXf, NX, NXP, 2, KA_OFF, KA_OFF, 1);
  qr(KA_OFF, NXP, 4, NX, SPLIT_QRX, S_OFF, SQRT_DXf, X_OFF, NX, ISQRT_DXf, -1, DOUT_X);

  // GL/GR grams of the (new) X — serve both S-phase and L-phase
  k_gram<<<dim3(SPLIT_X,2,2),256,0,stream>>>(W, 5, X_OFF, NX, -1, 0.f,0.f, PART_OFF, NX, SPLIT_X);
  k_reduce2<<<dim3(2,16,2),256,0,stream>>>(W, PART_OFF, GLR_OFF, SPLIT_X);

  // ---------- Poisson #2 + S-step ----------
  poisson();
  k_gram<<<dim3(SPLIT_X,2,2),256,0,stream>>>(W, 3, X_OFF, NX, E_OFF, 1.0f, 1.0f, PART_OFF, NX, SPLIT_X);
  k_reduce2<<<dim3(2,16,2),256,0,stream>>>(W, PART_OFF, SM_OFF + 2*4096, SPLIT_X);
  k_sstep<<<dim3(2),256,0,stream>>>(W, 1);
  k_sstep<<<dim3(2),256,0,stream>>>(W, 2);

  // ---------- Poisson #3 + L-step ----------
  poisson();
  k_gram<<<dim3(SPLIT_X,2,2),256,0,stream>>>(W, 3, X_OFF, NX, E_OFF, FAC_E, FAC_I, PART_OFF, NX, SPLIT_X);
  k_reduce2<<<dim3(2,16,2),256,0,stream>>>(W, PART_OFF, SM_OFF + 2*4096, SPLIT_X);
  k_rr<<<dim3(NV/64,1,2),256,0,stream>>>(W, S_OFF, 1, V_OFF, NV, 0, LA_OFF, NVP, 4, -1, 1.0f, nullptr, -1);
  auto leval = [&](int Lsrc, int stage, int Ldst, int Lorig) {
    qr(Lsrc, NVP, 4, NV, SPLIT_QRV, SQ_OFF, SQRT_DVf, VQ_OFF, NV, ISQRT_DVf, -1, -1);
    k_gram<<<dim3(SPLIT_VM,2,2),256,0,stream>>>(W, 1, VQ_OFF, NV, -1, 0.f,0.f, PART_OFF, NV, SPLIT_VM);
    k_reduce2<<<dim3(2,16,2),256,0,stream>>>(W, PART_OFF, MATS_OFF + 6*4096, SPLIT_VM);
    k_klr<<<dim3(2),256,0,stream>>>(W, SQ_OFF, 6, 7);
    k_flux<<<dim3(NV/32,1,2),256,0,stream>>>(W, Lsrc, VQ_OFF, NV, 0, 0,
        SM_OFF+2*4096, SM_OFF+3*4096, SM_OFF+0*4096, SM_OFF+1*4096,
        -1, 0.f, 0.f, 1.0f/DVf, NV, NVP, stage, Lorig, Ldst, 0);
  };
  leval(LA_OFF, 1, LB_OFF, 0);
  leval(LB_OFF, 2, LA_OFF, LA_OFF);
  qr(LA_OFF, NVP, 4, NV, SPLIT_QRV, S_OFF, SQRT_DVf, V_OFF, NV, ISQRT_DVf, DOUT_S, DOUT_V);

  (void)in_sizes; (void)n_in; (void)out_size; (void)ws_size;
}